// Round 1
// baseline (1370.759 us; speedup 1.0000x reference)
//
#include <hip/hip_runtime.h>
#include <hip/hip_bf16.h>
#include <stdint.h>

#define N_SUP 16384
#define DIM   1024
#define NLV   4
#define NCLS  64

typedef __bf16 bf16x8 __attribute__((ext_vector_type(8)));
typedef float  f32x4  __attribute__((ext_vector_type(4)));

// ---------------- conversions ----------------
__global__ __launch_bounds__(256) void k_conv_feat(const float* __restrict__ f,
                                                   __bf16* __restrict__ o) {
    size_t i = ((size_t)blockIdx.x * 256 + threadIdx.x) * 4;
    float4 v = *(const float4*)(f + i);
    union { __bf16 b[4]; uint64_t u; } pk;
    pk.b[0] = (__bf16)v.x; pk.b[1] = (__bf16)v.y;
    pk.b[2] = (__bf16)v.z; pk.b[3] = (__bf16)v.w;
    *(uint64_t*)(o + i) = pk.u;
}

// transpose+convert an_w1[l][:1024][:] and an_w2[l] into N-major (N x K) bf16
__global__ __launch_bounds__(256) void k_wt(const float* __restrict__ an_w1,
                                            const float* __restrict__ an_w2,
                                            __bf16* __restrict__ w1t,
                                            __bf16* __restrict__ w2t) {
    __shared__ float tile[64][65];
    int m = blockIdx.z;
    const float* src; __bf16* dst;
    if (m < 4) { src = an_w1 + (size_t)m * 1025 * 1024; dst = w1t + (size_t)m * 1024 * 1024; }
    else       { src = an_w2 + (size_t)(m - 4) * 1024 * 1024; dst = w2t + (size_t)(m - 4) * 1024 * 1024; }
    int k0 = blockIdx.x * 64, n0 = blockIdx.y * 64;
    int j = threadIdx.x & 63, i0 = threadIdx.x >> 6;
    #pragma unroll
    for (int ii = 0; ii < 16; ++ii) {
        int i = i0 + ii * 4;
        tile[i][j] = src[(size_t)(k0 + i) * 1024 + n0 + j];
    }
    __syncthreads();
    #pragma unroll
    for (int ii = 0; ii < 16; ++ii) {
        int i = i0 + ii * 4;
        dst[(size_t)(n0 + i) * 1024 + k0 + j] = (__bf16)tile[j][i];   // dst[n][k]=src[k][n]
    }
}

// eff_b1[l][j] = an_b1[l][j] + lvl_emb[l] * an_w1[l][1024][j]
__global__ __launch_bounds__(256) void k_eff_b1(const float* __restrict__ an_w1,
                                                const float* __restrict__ an_b1,
                                                const float* __restrict__ lvl_emb,
                                                float* __restrict__ eff) {
    int i = blockIdx.x * 256 + threadIdx.x;      // 0..4095
    int l = i >> 10, j = i & 1023;
    eff[i] = an_b1[i] + lvl_emb[l] * an_w1[(size_t)l * 1025 * 1024 + (size_t)1024 * 1024 + j];
}

__global__ __launch_bounds__(256) void k_counts(const int* __restrict__ labels,
                                                float* __restrict__ counts_f) {
    __shared__ int cnt[NCLS];
    int tid = threadIdx.x;
    if (tid < NCLS) cnt[tid] = 0;
    __syncthreads();
    for (int i = tid; i < N_SUP; i += 256) atomicAdd(&cnt[labels[i]], 1);
    __syncthreads();
    if (tid < NCLS) counts_f[tid] = fmaxf((float)cnt[tid], 1.0f);
}

// per-class raw sums + column totals (for task_context), one pass over features
__global__ __launch_bounds__(256) void k_feat_stats(const float* __restrict__ X,
                                                    const int* __restrict__ labels,
                                                    float* __restrict__ rawsum,
                                                    float* __restrict__ tasksum) {
    __shared__ float cls[NCLS][64];
    int tid = threadIdx.x;
    for (int i = tid; i < NCLS * 64; i += 256) ((float*)cls)[i] = 0.f;
    __syncthreads();
    int cb = blockIdx.x, rs = blockIdx.y;
    int lane = tid & 63, w = tid >> 6;
    int col = cb * 64 + lane;
    float tot = 0.f;
    for (int r = rs * 1024 + w; r < rs * 1024 + 1024; r += 4) {
        int lab = labels[r];
        float val = X[(size_t)r * DIM + col];
        tot += val;
        atomicAdd(&cls[lab][lane], val);
    }
    atomicAdd(&tasksum[col], tot);
    __syncthreads();
    for (int i = tid; i < NCLS * 64; i += 256) {
        int lab = i >> 6, c2 = i & 63;
        atomicAdd(&rawsum[(size_t)lab * DIM + cb * 64 + c2], cls[lab][c2]);
    }
}

__global__ __launch_bounds__(256) void k_segsum(const float* __restrict__ X,
                                                const int* __restrict__ labels,
                                                float* __restrict__ outp) {
    __shared__ float cls[NCLS][64];
    int tid = threadIdx.x;
    for (int i = tid; i < NCLS * 64; i += 256) ((float*)cls)[i] = 0.f;
    __syncthreads();
    int cb = blockIdx.x, rs = blockIdx.y;
    int lane = tid & 63, w = tid >> 6;
    int col = cb * 64 + lane;
    for (int r = rs * 1024 + w; r < rs * 1024 + 1024; r += 4) {
        int lab = labels[r];
        float val = X[(size_t)r * DIM + col];
        atomicAdd(&cls[lab][lane], val);
    }
    __syncthreads();
    for (int i = tid; i < NCLS * 64; i += 256) {
        int lab = i >> 6, c2 = i & 63;
        atomicAdd(&outp[(size_t)lab * DIM + cb * 64 + c2], cls[lab][c2]);
    }
}

// exact f32 head: task mean -> MLP -> acts -> mask/slots/k ; writes acts & level_contributions
__global__ __launch_bounds__(512) void k_head(const float* __restrict__ tasksum,
                                              const float* __restrict__ sp_w1,
                                              const float* __restrict__ sp_b1,
                                              const float* __restrict__ sp_w2,
                                              const float* __restrict__ sp_b2,
                                              float* __restrict__ headf,
                                              int* __restrict__ headi,
                                              float* __restrict__ dout) {
    __shared__ float tc[1024];
    __shared__ float h[512];
    __shared__ float a4[4];
    int tid = threadIdx.x;
    tc[tid]       = tasksum[tid]       * (1.0f / N_SUP);
    tc[tid + 512] = tasksum[tid + 512] * (1.0f / N_SUP);
    __syncthreads();
    float acc = 0.f;
    for (int k = 0; k < 1024; ++k) acc += tc[k] * sp_w1[(size_t)k * 512 + tid];
    acc += sp_b1[tid];
    h[tid] = acc > 0.f ? acc : 0.f;
    __syncthreads();
    if (tid < 4) {
        float s = 0.f;
        for (int k = 0; k < 512; ++k) s += h[k] * sp_w2[k * 4 + tid];
        s += sp_b2[tid];
        a4[tid] = 1.0f / (1.0f + expf(-s));
    }
    __syncthreads();
    if (tid == 0) {
        int kk = 0;
        int lvl[4] = {-1, -1, -1, -1};
        for (int l = 0; l < 4; ++l)
            if (a4[l] > 0.1f) { lvl[kk] = l; kk++; }
        headi[0] = kk;
        for (int s = 0; s < 4; ++s) headi[1 + s] = lvl[s];
        for (int l = 0; l < 4; ++l) headf[l] = a4[l];
    }
    if (tid < 4) {
        dout[65536 + tid] = a4[tid];
        dout[65540 + tid] = a4[tid] > 0.1f ? a4[tid] : 0.f;
    }
}

// bf16 MFMA GEMM: C = A(MxK) * Bt(NxK)^T + bias, 128x128 tile, 4 waves 2x2, BK=32
__global__ __launch_bounds__(256) void k_gemm(const __bf16* __restrict__ A,
                                              const __bf16* __restrict__ Bt,
                                              const float* __restrict__ bias,
                                              float* __restrict__ C,
                                              int M, int Nn, int K) {
    __shared__ __bf16 As[128][40];   // pad 32->40 : 80B row stride, 2-way banks (free)
    __shared__ __bf16 Bs[128][40];
    int tid = threadIdx.x;
    int lane = tid & 63;
    int w = tid >> 6;
    int wr = w >> 1, wc = w & 1;
    size_t bm = (size_t)blockIdx.x * 128;
    size_t bn = (size_t)blockIdx.y * 128;
    f32x4 acc[4][4] = {};
    int r0 = tid >> 2;            // 0..63: row unit
    int kp = (tid & 3) * 8;       // bf16 offset within row
    int kk = (lane >> 4) * 8;     // frag k-offset
    int am = lane & 15;
    for (int k0 = 0; k0 < K; k0 += 32) {
        uint4 av0 = *(const uint4*)(A  + (bm + r0)      * K + k0 + kp);
        uint4 av1 = *(const uint4*)(A  + (bm + 64 + r0) * K + k0 + kp);
        uint4 bv0 = *(const uint4*)(Bt + (bn + r0)      * K + k0 + kp);
        uint4 bv1 = *(const uint4*)(Bt + (bn + 64 + r0) * K + k0 + kp);
        __syncthreads();
        *(uint4*)(&As[r0][kp])      = av0;
        *(uint4*)(&As[64 + r0][kp]) = av1;
        *(uint4*)(&Bs[r0][kp])      = bv0;
        *(uint4*)(&Bs[64 + r0][kp]) = bv1;
        __syncthreads();
        bf16x8 af[4], bfr[4];
        #pragma unroll
        for (int mi = 0; mi < 4; ++mi)
            af[mi] = *(const bf16x8*)(&As[wr * 64 + mi * 16 + am][kk]);
        #pragma unroll
        for (int ni = 0; ni < 4; ++ni)
            bfr[ni] = *(const bf16x8*)(&Bs[wc * 64 + ni * 16 + am][kk]);
        #pragma unroll
        for (int mi = 0; mi < 4; ++mi)
            #pragma unroll
            for (int ni = 0; ni < 4; ++ni)
                acc[mi][ni] = __builtin_amdgcn_mfma_f32_16x16x32_bf16(af[mi], bfr[ni], acc[mi][ni], 0, 0, 0);
    }
    int rbase = (lane >> 4) * 4;     // C/D: col=lane&15, row=(lane>>4)*4+reg
    #pragma unroll
    for (int mi = 0; mi < 4; ++mi) {
        size_t row = bm + wr * 64 + mi * 16 + rbase;
        #pragma unroll
        for (int ni = 0; ni < 4; ++ni) {
            int col = (int)bn + wc * 64 + ni * 16 + am;
            float bv = bias[col];
            #pragma unroll
            for (int r = 0; r < 4; ++r)
                C[(row + r) * Nn + col] = acc[mi][ni][r] + bv;
        }
    }
}

__global__ __launch_bounds__(256) void k_ln_relu(const float* __restrict__ hh,
                                                 const float* __restrict__ gamma,
                                                 const float* __restrict__ beta,
                                                 __bf16* __restrict__ outp) {
    __shared__ float ss[4], qq[4], mv[2];
    int row = blockIdx.x;
    int tid = threadIdx.x;
    float4 v = *(const float4*)(hh + (size_t)row * DIM + tid * 4);
    float s = v.x + v.y + v.z + v.w;
    float q = v.x * v.x + v.y * v.y + v.z * v.z + v.w * v.w;
    #pragma unroll
    for (int off = 32; off > 0; off >>= 1) {
        s += __shfl_down(s, off);
        q += __shfl_down(q, off);
    }
    int w = tid >> 6;
    if ((tid & 63) == 0) { ss[w] = s; qq[w] = q; }
    __syncthreads();
    if (tid == 0) {
        float S = ss[0] + ss[1] + ss[2] + ss[3];
        float Q = qq[0] + qq[1] + qq[2] + qq[3];
        float mu = S * (1.0f / DIM);
        float var = Q * (1.0f / DIM) - mu * mu;
        mv[0] = mu;
        mv[1] = rsqrtf(var + 1e-5f);
    }
    __syncthreads();
    float mu = mv[0], rstd = mv[1];
    union { __bf16 b[4]; uint64_t u; } pk;
    float* vp = &v.x;
    #pragma unroll
    for (int j = 0; j < 4; ++j) {
        int colj = tid * 4 + j;
        float x = (vp[j] - mu) * rstd * gamma[colj] + beta[colj];
        pk.b[j] = (__bf16)(x > 0.f ? x : 0.f);
    }
    *(uint64_t*)(outp + (size_t)row * DIM + tid * 4) = pk.u;
}

// fusion_input build: fi is 64 x 4160 (zero-padded beyond S=4100)
__global__ __launch_bounds__(256) void k_build_fi(const float* __restrict__ psum,
                                                  const float* __restrict__ counts_f,
                                                  const float* __restrict__ headf,
                                                  const int* __restrict__ headi,
                                                  float* __restrict__ fi) {
    int idx = blockIdx.x * 256 + threadIdx.x;
    if (idx >= 64 * 4160) return;
    int c = idx / 4160, col = idx % 4160;
    int kk = headi[0];
    float v = 0.f;
    if (col < kk * 1024) {
        int s = col >> 10, d = col & 1023;
        int l = headi[1 + s];
        v = psum[((size_t)l * NCLS + c) * DIM + d] / counts_f[c];
    } else if (col < kk * 1024 + kk) {
        int s = col - kk * 1024;
        v = headf[headi[1 + s]];
    }
    fi[idx] = v;
}

// small f32 GEMM (64 x 1024 out), K split across grid.y slices, atomic accumulate
__global__ __launch_bounds__(256) void k_small_gemm_acc(const float* __restrict__ Afi,
                                                        const float* __restrict__ W,
                                                        float* __restrict__ outp,
                                                        int lda, int K, int cps) {
    __shared__ float fi_lds[64][64];
    int tid = threadIdx.x;
    int tj = tid & 63, tg = tid >> 6;
    int jb = blockIdx.x;
    int nch = (lda + 63) / 64;
    int c0 = blockIdx.y * cps;
    int cend = c0 + cps < nch ? c0 + cps : nch;
    float acc[16] = {};
    for (int ch = c0; ch < cend; ++ch) {
        int kbase = ch * 64;
        __syncthreads();
        for (int i = tid; i < 64 * 64; i += 256) {
            int cc = i >> 6, kq = i & 63;
            fi_lds[cc][kq] = Afi[(size_t)cc * lda + kbase + kq];
        }
        __syncthreads();
        for (int kq = 0; kq < 64; ++kq) {
            int kg = kbase + kq;
            float wv = (kg < K) ? W[(size_t)kg * 1024 + jb * 64 + tj] : 0.f;
            #pragma unroll
            for (int cc = 0; cc < 16; ++cc)
                acc[cc] += fi_lds[tg * 16 + cc][kq] * wv;
        }
    }
    #pragma unroll
    for (int cc = 0; cc < 16; ++cc)
        atomicAdd(&outp[(size_t)(tg * 16 + cc) * 1024 + jb * 64 + tj], acc[cc]);
}

__global__ __launch_bounds__(256) void k_bias_relu(const float* __restrict__ pre,
                                                   const float* __restrict__ b,
                                                   float* __restrict__ outp) {
    int i = blockIdx.x * 256 + threadIdx.x;   // 65536
    int j = i & 1023;
    float v = pre[i] + b[j];
    outp[i] = v > 0.f ? v : 0.f;
}

__global__ __launch_bounds__(256) void k_final(const float* __restrict__ pre2,
                                               const float* __restrict__ fu_b2,
                                               const int* __restrict__ headi,
                                               const float* __restrict__ rawsum,
                                               const float* __restrict__ counts_f,
                                               float* __restrict__ dout) {
    int i = blockIdx.x * 256 + threadIdx.x;   // 65536
    int c = i >> 10, j = i & 1023;
    float v;
    if (headi[0] > 0) v = pre2[i] + fu_b2[j];
    else              v = rawsum[i] / counts_f[c];
    dout[i] = v;
}

extern "C" void kernel_launch(void* const* d_in, const int* in_sizes, int n_in,
                              void* d_out, int out_size, void* d_ws, size_t ws_size,
                              hipStream_t stream) {
    (void)in_sizes; (void)n_in; (void)out_size; (void)ws_size;
    const float* feat    = (const float*)d_in[0];
    const int*   labels  = (const int*)d_in[1];
    const float* sp_w1   = (const float*)d_in[2];
    const float* sp_b1   = (const float*)d_in[3];
    const float* sp_w2   = (const float*)d_in[4];
    const float* sp_b2   = (const float*)d_in[5];
    const float* lvl_emb = (const float*)d_in[6];
    const float* an_w1   = (const float*)d_in[7];
    const float* an_b1   = (const float*)d_in[8];
    const float* an_g    = (const float*)d_in[9];
    const float* an_be   = (const float*)d_in[10];
    const float* an_w2   = (const float*)d_in[11];
    const float* an_b2   = (const float*)d_in[12];
    const float* fu_w1   = (const float*)d_in[13];
    const float* fu_b1   = (const float*)d_in[14];
    const float* fu_w2   = (const float*)d_in[15];
    const float* fu_b2   = (const float*)d_in[16];
    float* dout = (float*)d_out;

    char* p = (char*)d_ws;
    auto alloc = [&](size_t b) { char* r = p; p += (b + 255) & ~(size_t)255; return r; };
    __bf16* featb = (__bf16*)alloc((size_t)N_SUP * DIM * 2);
    __bf16* w1t   = (__bf16*)alloc((size_t)NLV * DIM * DIM * 2);
    __bf16* w2t   = (__bf16*)alloc((size_t)NLV * DIM * DIM * 2);
    float*  hh    = (float*) alloc((size_t)N_SUP * DIM * 4);   // reused as t
    __bf16* hhp   = (__bf16*)alloc((size_t)N_SUP * DIM * 2);
    float*  effb1 = (float*) alloc((size_t)NLV * DIM * 4);
    float*  fi    = (float*) alloc((size_t)64 * 4160 * 4);
    float*  h1    = (float*) alloc((size_t)NCLS * DIM * 4);
    char* z0 = p;
    float* tasksum  = (float*)alloc(DIM * 4);
    float* counts_f = (float*)alloc(NCLS * 4);
    float* rawsum   = (float*)alloc((size_t)NCLS * DIM * 4);
    float* psum     = (float*)alloc((size_t)NLV * NCLS * DIM * 4);
    float* h1pre    = (float*)alloc((size_t)NCLS * DIM * 4);
    float* f2pre    = (float*)alloc((size_t)NCLS * DIM * 4);
    float* headf    = (float*)alloc(4 * 4);
    int*   headi    = (int*)  alloc(8 * 4);
    size_t zbytes = (size_t)(p - z0);
    hipMemsetAsync(z0, 0, zbytes, stream);

    k_conv_feat<<<N_SUP * DIM / 4 / 256, 256, 0, stream>>>(feat, featb);
    k_wt<<<dim3(16, 16, 8), 256, 0, stream>>>(an_w1, an_w2, w1t, w2t);
    k_eff_b1<<<16, 256, 0, stream>>>(an_w1, an_b1, lvl_emb, effb1);
    k_counts<<<1, 256, 0, stream>>>(labels, counts_f);
    k_feat_stats<<<dim3(16, 16), 256, 0, stream>>>(feat, labels, rawsum, tasksum);
    k_head<<<1, 512, 0, stream>>>(tasksum, sp_w1, sp_b1, sp_w2, sp_b2, headf, headi, dout);

    for (int l = 0; l < NLV; ++l) {
        k_gemm<<<dim3(128, 8), 256, 0, stream>>>(featb, w1t + (size_t)l * DIM * DIM,
                                                 effb1 + l * DIM, hh, N_SUP, DIM, DIM);
        k_ln_relu<<<N_SUP, 256, 0, stream>>>(hh, an_g + l * DIM, an_be + l * DIM, hhp);
        k_gemm<<<dim3(128, 8), 256, 0, stream>>>(hhp, w2t + (size_t)l * DIM * DIM,
                                                 an_b2 + l * DIM, hh, N_SUP, DIM, DIM);
        k_segsum<<<dim3(16, 16), 256, 0, stream>>>(hh, labels, psum + (size_t)l * NCLS * DIM);
    }

    k_build_fi<<<(64 * 4160) / 256, 256, 0, stream>>>(psum, counts_f, headf, headi, fi);
    k_small_gemm_acc<<<dim3(16, 5), 256, 0, stream>>>(fi, fu_w1, h1pre, 4160, 4100, 13);
    k_bias_relu<<<NCLS * DIM / 256, 256, 0, stream>>>(h1pre, fu_b1, h1);
    k_small_gemm_acc<<<dim3(16, 4), 256, 0, stream>>>(h1, fu_w2, f2pre, 1024, 1024, 4);
    k_final<<<NCLS * DIM / 256, 256, 0, stream>>>(f2pre, fu_b2, headi, rawsum, counts_f, dout);
}

// Round 2
// 1118.761 us; speedup vs baseline: 1.2252x; 1.2252x over previous
//
#include <hip/hip_runtime.h>
#include <hip/hip_bf16.h>
#include <stdint.h>

#define N_SUP 16384
#define DIM   1024
#define NLV   4
#define NCLS  64

typedef __bf16 bf16x8 __attribute__((ext_vector_type(8)));
typedef float  f32x4  __attribute__((ext_vector_type(4)));

#define GLOAD_LDS16(g, l) \
    __builtin_amdgcn_global_load_lds((const __attribute__((address_space(1))) void*)(g), \
                                     (__attribute__((address_space(3))) void*)(l), 16, 0, 0)

// ---------------- conversions ----------------
__global__ __launch_bounds__(256) void k_conv_feat(const float* __restrict__ f,
                                                   __bf16* __restrict__ o) {
    size_t i = ((size_t)blockIdx.x * 256 + threadIdx.x) * 4;
    float4 v = *(const float4*)(f + i);
    union { __bf16 b[4]; uint64_t u; } pk;
    pk.b[0] = (__bf16)v.x; pk.b[1] = (__bf16)v.y;
    pk.b[2] = (__bf16)v.z; pk.b[3] = (__bf16)v.w;
    *(uint64_t*)(o + i) = pk.u;
}

// transpose+convert an_w1[l][:1024][:] and an_w2[l] into N-major (N x K) bf16
__global__ __launch_bounds__(256) void k_wt(const float* __restrict__ an_w1,
                                            const float* __restrict__ an_w2,
                                            __bf16* __restrict__ w1t,
                                            __bf16* __restrict__ w2t) {
    __shared__ float tile[64][65];
    int m = blockIdx.z;
    const float* src; __bf16* dst;
    if (m < 4) { src = an_w1 + (size_t)m * 1025 * 1024; dst = w1t + (size_t)m * 1024 * 1024; }
    else       { src = an_w2 + (size_t)(m - 4) * 1024 * 1024; dst = w2t + (size_t)(m - 4) * 1024 * 1024; }
    int k0 = blockIdx.x * 64, n0 = blockIdx.y * 64;
    int j = threadIdx.x & 63, i0 = threadIdx.x >> 6;
    #pragma unroll
    for (int ii = 0; ii < 16; ++ii) {
        int i = i0 + ii * 4;
        tile[i][j] = src[(size_t)(k0 + i) * 1024 + n0 + j];
    }
    __syncthreads();
    #pragma unroll
    for (int ii = 0; ii < 16; ++ii) {
        int i = i0 + ii * 4;
        dst[(size_t)(n0 + i) * 1024 + k0 + j] = (__bf16)tile[j][i];   // dst[n][k]=src[k][n]
    }
}

// eff_b1[l][j] = an_b1[l][j] + lvl_emb[l] * an_w1[l][1024][j]
__global__ __launch_bounds__(256) void k_eff_b1(const float* __restrict__ an_w1,
                                                const float* __restrict__ an_b1,
                                                const float* __restrict__ lvl_emb,
                                                float* __restrict__ eff) {
    int i = blockIdx.x * 256 + threadIdx.x;      // 0..4095
    int l = i >> 10, j = i & 1023;
    eff[i] = an_b1[i] + lvl_emb[l] * an_w1[(size_t)l * 1025 * 1024 + (size_t)1024 * 1024 + j];
}

__global__ __launch_bounds__(256) void k_counts(const int* __restrict__ labels,
                                                float* __restrict__ counts_f) {
    __shared__ int cnt[NCLS];
    int tid = threadIdx.x;
    if (tid < NCLS) cnt[tid] = 0;
    __syncthreads();
    for (int i = tid; i < N_SUP; i += 256) atomicAdd(&cnt[labels[i]], 1);
    __syncthreads();
    if (tid < NCLS) counts_f[tid] = fmaxf((float)cnt[tid], 1.0f);
}

// per-class raw sums + column totals (for task_context), one pass over features
__global__ __launch_bounds__(256) void k_feat_stats(const float* __restrict__ X,
                                                    const int* __restrict__ labels,
                                                    float* __restrict__ rawsum,
                                                    float* __restrict__ tasksum) {
    __shared__ float cls[NCLS][64];
    int tid = threadIdx.x;
    for (int i = tid; i < NCLS * 64; i += 256) ((float*)cls)[i] = 0.f;
    __syncthreads();
    int cb = blockIdx.x, rs = blockIdx.y;
    int lane = tid & 63, w = tid >> 6;
    int col = cb * 64 + lane;
    float tot = 0.f;
    for (int r = rs * 1024 + w; r < rs * 1024 + 1024; r += 4) {
        int lab = labels[r];
        float val = X[(size_t)r * DIM + col];
        tot += val;
        atomicAdd(&cls[lab][lane], val);
    }
    atomicAdd(&tasksum[col], tot);
    __syncthreads();
    for (int i = tid; i < NCLS * 64; i += 256) {
        int lab = i >> 6, c2 = i & 63;
        atomicAdd(&rawsum[(size_t)lab * DIM + cb * 64 + c2], cls[lab][c2]);
    }
}

__global__ __launch_bounds__(256) void k_segsum(const float* __restrict__ X,
                                                const int* __restrict__ labels,
                                                float* __restrict__ outp) {
    __shared__ float cls[NCLS][64];
    int tid = threadIdx.x;
    for (int i = tid; i < NCLS * 64; i += 256) ((float*)cls)[i] = 0.f;
    __syncthreads();
    int cb = blockIdx.x, rs = blockIdx.y;
    int lane = tid & 63, w = tid >> 6;
    int col = cb * 64 + lane;
    for (int r = rs * 1024 + w; r < rs * 1024 + 1024; r += 4) {
        int lab = labels[r];
        float val = X[(size_t)r * DIM + col];
        atomicAdd(&cls[lab][lane], val);
    }
    __syncthreads();
    for (int i = tid; i < NCLS * 64; i += 256) {
        int lab = i >> 6, c2 = i & 63;
        atomicAdd(&outp[(size_t)lab * DIM + cb * 64 + c2], cls[lab][c2]);
    }
}

// exact f32 head
__global__ __launch_bounds__(512) void k_head(const float* __restrict__ tasksum,
                                              const float* __restrict__ sp_w1,
                                              const float* __restrict__ sp_b1,
                                              const float* __restrict__ sp_w2,
                                              const float* __restrict__ sp_b2,
                                              float* __restrict__ headf,
                                              int* __restrict__ headi,
                                              float* __restrict__ dout) {
    __shared__ float tc[1024];
    __shared__ float h[512];
    __shared__ float a4[4];
    int tid = threadIdx.x;
    tc[tid]       = tasksum[tid]       * (1.0f / N_SUP);
    tc[tid + 512] = tasksum[tid + 512] * (1.0f / N_SUP);
    __syncthreads();
    float acc = 0.f;
    for (int k = 0; k < 1024; ++k) acc += tc[k] * sp_w1[(size_t)k * 512 + tid];
    acc += sp_b1[tid];
    h[tid] = acc > 0.f ? acc : 0.f;
    __syncthreads();
    if (tid < 4) {
        float s = 0.f;
        for (int k = 0; k < 512; ++k) s += h[k] * sp_w2[k * 4 + tid];
        s += sp_b2[tid];
        a4[tid] = 1.0f / (1.0f + expf(-s));
    }
    __syncthreads();
    if (tid == 0) {
        int kk = 0;
        int lvl[4] = {-1, -1, -1, -1};
        for (int l = 0; l < 4; ++l)
            if (a4[l] > 0.1f) { lvl[kk] = l; kk++; }
        headi[0] = kk;
        for (int s = 0; s < 4; ++s) headi[1 + s] = lvl[s];
        for (int l = 0; l < 4; ++l) headf[l] = a4[l];
    }
    if (tid < 4) {
        dout[65536 + tid] = a4[tid];
        dout[65540 + tid] = a4[tid] > 0.1f ? a4[tid] : 0.f;
    }
}

// bf16 MFMA GEMM, m97 structure: 128x128 tile, BK=32, 4 waves 2x2,
// global_load_lds width-16 staging into linear [128][32] LDS.
__global__ __launch_bounds__(256) void k_gemm(const __bf16* __restrict__ A,
                                              const __bf16* __restrict__ Bt,
                                              const float* __restrict__ bias,
                                              float* __restrict__ C,
                                              int M, int Nn, int K) {
    __shared__ __align__(16) __bf16 As[128 * 32];   // linear row-major [128][32]
    __shared__ __align__(16) __bf16 Bs[128 * 32];
    int tid = threadIdx.x;
    int lane = tid & 63;
    int w = tid >> 6;                 // wave 0..3
    int wr = w >> 1, wc = w & 1;
    size_t bm = (size_t)blockIdx.x * 128;
    size_t bn = (size_t)blockIdx.y * 128;
    f32x4 acc[4][4] = {};

    // staging: chunk c (0..7) = rows c*16..c*16+15 of the tile; 1KB per chunk.
    // wave w stages chunks {w, w+4} of A and of B. lane l -> row c*16+(l>>2), col (l&3)*8.
    int srow0 = w * 16 + (lane >> 2);
    int srow1 = (w + 4) * 16 + (lane >> 2);
    int scol  = (lane & 3) * 8;
    const __bf16* ga0 = A  + (bm + srow0) * K + scol;
    const __bf16* ga1 = A  + (bm + srow1) * K + scol;
    const __bf16* gb0 = Bt + (bn + srow0) * K + scol;
    const __bf16* gb1 = Bt + (bn + srow1) * K + scol;
    __bf16* la0 = As + (size_t)w * 512;          // 512 bf16 = 1KB
    __bf16* la1 = As + (size_t)(w + 4) * 512;
    __bf16* lb0 = Bs + (size_t)w * 512;
    __bf16* lb1 = Bs + (size_t)(w + 4) * 512;

    int am = lane & 15;
    int kko = (lane >> 4) * 8;        // frag k offset (bf16 elems)

    for (int k0 = 0; k0 < K; k0 += 32) {
        __syncthreads();              // previous tile fully consumed
        GLOAD_LDS16(ga0 + k0, la0);
        GLOAD_LDS16(ga1 + k0, la1);
        GLOAD_LDS16(gb0 + k0, lb0);
        GLOAD_LDS16(gb1 + k0, lb1);
        __syncthreads();              // drains vmcnt(0): LDS tile ready
        bf16x8 af[4], bfr[4];
        #pragma unroll
        for (int mi = 0; mi < 4; ++mi)
            af[mi] = *(const bf16x8*)(As + (wr * 64 + mi * 16 + am) * 32 + kko);
        #pragma unroll
        for (int ni = 0; ni < 4; ++ni)
            bfr[ni] = *(const bf16x8*)(Bs + (wc * 64 + ni * 16 + am) * 32 + kko);
        #pragma unroll
        for (int mi = 0; mi < 4; ++mi)
            #pragma unroll
            for (int ni = 0; ni < 4; ++ni)
                acc[mi][ni] = __builtin_amdgcn_mfma_f32_16x16x32_bf16(af[mi], bfr[ni], acc[mi][ni], 0, 0, 0);
    }
    int rbase = (lane >> 4) * 4;      // C/D: col=lane&15, row=(lane>>4)*4+reg
    #pragma unroll
    for (int mi = 0; mi < 4; ++mi) {
        size_t row = bm + wr * 64 + mi * 16 + rbase;
        #pragma unroll
        for (int ni = 0; ni < 4; ++ni) {
            int col = (int)bn + wc * 64 + ni * 16 + am;
            float bv = bias[col];
            #pragma unroll
            for (int r = 0; r < 4; ++r)
                C[(row + r) * Nn + col] = acc[mi][ni][r] + bv;
        }
    }
}

__global__ __launch_bounds__(256) void k_ln_relu(const float* __restrict__ hh,
                                                 const float* __restrict__ gamma,
                                                 const float* __restrict__ beta,
                                                 __bf16* __restrict__ outp) {
    __shared__ float ss[4], qq[4], mv[2];
    int row = blockIdx.x;
    int tid = threadIdx.x;
    float4 v = *(const float4*)(hh + (size_t)row * DIM + tid * 4);
    float s = v.x + v.y + v.z + v.w;
    float q = v.x * v.x + v.y * v.y + v.z * v.z + v.w * v.w;
    #pragma unroll
    for (int off = 32; off > 0; off >>= 1) {
        s += __shfl_down(s, off);
        q += __shfl_down(q, off);
    }
    int w = tid >> 6;
    if ((tid & 63) == 0) { ss[w] = s; qq[w] = q; }
    __syncthreads();
    if (tid == 0) {
        float S = ss[0] + ss[1] + ss[2] + ss[3];
        float Q = qq[0] + qq[1] + qq[2] + qq[3];
        float mu = S * (1.0f / DIM);
        float var = Q * (1.0f / DIM) - mu * mu;
        mv[0] = mu;
        mv[1] = rsqrtf(var + 1e-5f);
    }
    __syncthreads();
    float mu = mv[0], rstd = mv[1];
    union { __bf16 b[4]; uint64_t u; } pk;
    float* vp = &v.x;
    #pragma unroll
    for (int j = 0; j < 4; ++j) {
        int colj = tid * 4 + j;
        float x = (vp[j] - mu) * rstd * gamma[colj] + beta[colj];
        pk.b[j] = (__bf16)(x > 0.f ? x : 0.f);
    }
    *(uint64_t*)(outp + (size_t)row * DIM + tid * 4) = pk.u;
}

// fusion_input build: fi is 64 x 4160 (zero-padded beyond S=4100)
__global__ __launch_bounds__(256) void k_build_fi(const float* __restrict__ psum,
                                                  const float* __restrict__ counts_f,
                                                  const float* __restrict__ headf,
                                                  const int* __restrict__ headi,
                                                  float* __restrict__ fi) {
    int idx = blockIdx.x * 256 + threadIdx.x;
    if (idx >= 64 * 4160) return;
    int c = idx / 4160, col = idx % 4160;
    int kk = headi[0];
    float v = 0.f;
    if (col < kk * 1024) {
        int s = col >> 10, d = col & 1023;
        int l = headi[1 + s];
        v = psum[((size_t)l * NCLS + c) * DIM + d] / counts_f[c];
    } else if (col < kk * 1024 + kk) {
        int s = col - kk * 1024;
        v = headf[headi[1 + s]];
    }
    fi[idx] = v;
}

// fusion GEMM: one 64-wide K-chunk per block, massive split-K, atomic accumulate.
// out[64][1024] += fi(64 x lda)[:, k0:k0+64] @ W[k0:k0+64, :1024]
__global__ __launch_bounds__(256) void k_fuse_gemm(const float* __restrict__ Afi,
                                                   const float* __restrict__ W,
                                                   float* __restrict__ outp,
                                                   int lda, int K) {
    __shared__ float fi_lds[64][64];
    int tid = threadIdx.x;
    int tj = tid & 63, tg = tid >> 6;
    int jb = blockIdx.x;              // 16 blocks of 64 cols
    int k0 = blockIdx.y * 64;
    for (int i = tid; i < 64 * 64; i += 256) {
        int cc = i >> 6, kq = i & 63;
        fi_lds[cc][kq] = (k0 + kq < lda) ? Afi[(size_t)cc * lda + k0 + kq] : 0.f;
    }
    __syncthreads();
    float acc[16] = {};
    #pragma unroll 4
    for (int kq = 0; kq < 64; ++kq) {
        int kg = k0 + kq;
        float wv = (kg < K) ? W[(size_t)kg * 1024 + jb * 64 + tj] : 0.f;
        #pragma unroll
        for (int cc = 0; cc < 16; ++cc)
            acc[cc] += fi_lds[tg * 16 + cc][kq] * wv;
    }
    #pragma unroll
    for (int cc = 0; cc < 16; ++cc)
        atomicAdd(&outp[(size_t)(tg * 16 + cc) * 1024 + jb * 64 + tj], acc[cc]);
}

__global__ __launch_bounds__(256) void k_bias_relu(const float* __restrict__ pre,
                                                   const float* __restrict__ b,
                                                   float* __restrict__ outp) {
    int i = blockIdx.x * 256 + threadIdx.x;   // 65536
    int j = i & 1023;
    float v = pre[i] + b[j];
    outp[i] = v > 0.f ? v : 0.f;
}

__global__ __launch_bounds__(256) void k_final(const float* __restrict__ pre2,
                                               const float* __restrict__ fu_b2,
                                               const int* __restrict__ headi,
                                               const float* __restrict__ rawsum,
                                               const float* __restrict__ counts_f,
                                               float* __restrict__ dout) {
    int i = blockIdx.x * 256 + threadIdx.x;   // 65536
    int c = i >> 10, j = i & 1023;
    float v;
    if (headi[0] > 0) v = pre2[i] + fu_b2[j];
    else              v = rawsum[i] / counts_f[c];
    dout[i] = v;
}

extern "C" void kernel_launch(void* const* d_in, const int* in_sizes, int n_in,
                              void* d_out, int out_size, void* d_ws, size_t ws_size,
                              hipStream_t stream) {
    (void)in_sizes; (void)n_in; (void)out_size; (void)ws_size;
    const float* feat    = (const float*)d_in[0];
    const int*   labels  = (const int*)d_in[1];
    const float* sp_w1   = (const float*)d_in[2];
    const float* sp_b1   = (const float*)d_in[3];
    const float* sp_w2   = (const float*)d_in[4];
    const float* sp_b2   = (const float*)d_in[5];
    const float* lvl_emb = (const float*)d_in[6];
    const float* an_w1   = (const float*)d_in[7];
    const float* an_b1   = (const float*)d_in[8];
    const float* an_g    = (const float*)d_in[9];
    const float* an_be   = (const float*)d_in[10];
    const float* an_w2   = (const float*)d_in[11];
    const float* an_b2   = (const float*)d_in[12];
    const float* fu_w1   = (const float*)d_in[13];
    const float* fu_b1   = (const float*)d_in[14];
    const float* fu_w2   = (const float*)d_in[15];
    const float* fu_b2   = (const float*)d_in[16];
    float* dout = (float*)d_out;

    char* p = (char*)d_ws;
    auto alloc = [&](size_t b) { char* r = p; p += (b + 255) & ~(size_t)255; return r; };
    __bf16* featb = (__bf16*)alloc((size_t)N_SUP * DIM * 2);
    __bf16* w1t   = (__bf16*)alloc((size_t)NLV * DIM * DIM * 2);
    __bf16* w2t   = (__bf16*)alloc((size_t)NLV * DIM * DIM * 2);
    float*  hh    = (float*) alloc((size_t)N_SUP * DIM * 4);   // reused as t
    __bf16* hhp   = (__bf16*)alloc((size_t)N_SUP * DIM * 2);
    float*  effb1 = (float*) alloc((size_t)NLV * DIM * 4);
    float*  fi    = (float*) alloc((size_t)64 * 4160 * 4);
    float*  h1    = (float*) alloc((size_t)NCLS * DIM * 4);
    char* z0 = p;
    float* tasksum  = (float*)alloc(DIM * 4);
    float* counts_f = (float*)alloc(NCLS * 4);
    float* rawsum   = (float*)alloc((size_t)NCLS * DIM * 4);
    float* psum     = (float*)alloc((size_t)NLV * NCLS * DIM * 4);
    float* h1pre    = (float*)alloc((size_t)NCLS * DIM * 4);
    float* f2pre    = (float*)alloc((size_t)NCLS * DIM * 4);
    float* headf    = (float*)alloc(4 * 4);
    int*   headi    = (int*)  alloc(8 * 4);
    size_t zbytes = (size_t)(p - z0);
    hipMemsetAsync(z0, 0, zbytes, stream);

    k_conv_feat<<<N_SUP * DIM / 4 / 256, 256, 0, stream>>>(feat, featb);
    k_wt<<<dim3(16, 16, 8), 256, 0, stream>>>(an_w1, an_w2, w1t, w2t);
    k_eff_b1<<<16, 256, 0, stream>>>(an_w1, an_b1, lvl_emb, effb1);
    k_counts<<<1, 256, 0, stream>>>(labels, counts_f);
    k_feat_stats<<<dim3(16, 16), 256, 0, stream>>>(feat, labels, rawsum, tasksum);
    k_head<<<1, 512, 0, stream>>>(tasksum, sp_w1, sp_b1, sp_w2, sp_b2, headf, headi, dout);

    for (int l = 0; l < NLV; ++l) {
        k_gemm<<<dim3(128, 8), 256, 0, stream>>>(featb, w1t + (size_t)l * DIM * DIM,
                                                 effb1 + l * DIM, hh, N_SUP, DIM, DIM);
        k_ln_relu<<<N_SUP, 256, 0, stream>>>(hh, an_g + l * DIM, an_be + l * DIM, hhp);
        k_gemm<<<dim3(128, 8), 256, 0, stream>>>(hhp, w2t + (size_t)l * DIM * DIM,
                                                 an_b2 + l * DIM, hh, N_SUP, DIM, DIM);
        k_segsum<<<dim3(16, 16), 256, 0, stream>>>(hh, labels, psum + (size_t)l * NCLS * DIM);
    }

    k_build_fi<<<(64 * 4160) / 256, 256, 0, stream>>>(psum, counts_f, headf, headi, fi);
    k_fuse_gemm<<<dim3(16, 65), 256, 0, stream>>>(fi, fu_w1, h1pre, 4160, 4100);
    k_bias_relu<<<NCLS * DIM / 256, 256, 0, stream>>>(h1pre, fu_b1, h1);
    k_fuse_gemm<<<dim3(16, 16), 256, 0, stream>>>(h1, fu_w2, f2pre, 1024, 1024);
    k_final<<<NCLS * DIM / 256, 256, 0, stream>>>(f2pre, fu_b2, headi, rawsum, counts_f, dout);
}

// Round 3
// 767.354 us; speedup vs baseline: 1.7863x; 1.4579x over previous
//
#include <hip/hip_runtime.h>
#include <hip/hip_bf16.h>
#include <stdint.h>

#define N_SUP 16384
#define DIM   1024
#define NLV   4
#define NCLS  64

typedef __bf16 bf16x8 __attribute__((ext_vector_type(8)));
typedef __bf16 bf16x4 __attribute__((ext_vector_type(4)));
typedef float  f32x4  __attribute__((ext_vector_type(4)));

#define GLOAD_LDS16(g, l) \
    __builtin_amdgcn_global_load_lds((const __attribute__((address_space(1))) void*)(g), \
                                     (__attribute__((address_space(3))) void*)(l), 16, 0, 0)

// ---------------- conversions ----------------
__global__ __launch_bounds__(256) void k_conv_feat(const float* __restrict__ f,
                                                   __bf16* __restrict__ o) {
    size_t i = ((size_t)blockIdx.x * 256 + threadIdx.x) * 4;
    float4 v = *(const float4*)(f + i);
    union { __bf16 b[4]; uint64_t u; } pk;
    pk.b[0] = (__bf16)v.x; pk.b[1] = (__bf16)v.y;
    pk.b[2] = (__bf16)v.z; pk.b[3] = (__bf16)v.w;
    *(uint64_t*)(o + i) = pk.u;
}

// transpose+convert an_w1[l][:1024][:] and an_w2[l] into N-major (N x K) bf16
__global__ __launch_bounds__(256) void k_wt(const float* __restrict__ an_w1,
                                            const float* __restrict__ an_w2,
                                            __bf16* __restrict__ w1t,
                                            __bf16* __restrict__ w2t) {
    __shared__ float tile[64][65];
    int m = blockIdx.z;
    const float* src; __bf16* dst;
    if (m < 4) { src = an_w1 + (size_t)m * 1025 * 1024; dst = w1t + (size_t)m * 1024 * 1024; }
    else       { src = an_w2 + (size_t)(m - 4) * 1024 * 1024; dst = w2t + (size_t)(m - 4) * 1024 * 1024; }
    int k0 = blockIdx.x * 64, n0 = blockIdx.y * 64;
    int j = threadIdx.x & 63, i0 = threadIdx.x >> 6;
    #pragma unroll
    for (int ii = 0; ii < 16; ++ii) {
        int i = i0 + ii * 4;
        tile[i][j] = src[(size_t)(k0 + i) * 1024 + n0 + j];
    }
    __syncthreads();
    #pragma unroll
    for (int ii = 0; ii < 16; ++ii) {
        int i = i0 + ii * 4;
        dst[(size_t)(n0 + i) * 1024 + k0 + j] = (__bf16)tile[j][i];   // dst[n][k]=src[k][n]
    }
}

// eff_b1[l][j] = an_b1[l][j] + lvl_emb[l] * an_w1[l][1024][j]
__global__ __launch_bounds__(256) void k_eff_b1(const float* __restrict__ an_w1,
                                                const float* __restrict__ an_b1,
                                                const float* __restrict__ lvl_emb,
                                                float* __restrict__ eff) {
    int i = blockIdx.x * 256 + threadIdx.x;      // 0..4095
    int l = i >> 10, j = i & 1023;
    eff[i] = an_b1[i] + lvl_emb[l] * an_w1[(size_t)l * 1025 * 1024 + (size_t)1024 * 1024 + j];
}

// build per-class row lists: counts, starts, scattered row indices. One block.
__global__ __launch_bounds__(1024) void k_rowlist(const int* __restrict__ labels,
                                                  int* __restrict__ rowlist,
                                                  int* __restrict__ gstart,
                                                  int* __restrict__ gcnt,
                                                  float* __restrict__ counts_f) {
    __shared__ int cnt[NCLS];
    __shared__ int sstart[NCLS];
    __shared__ int cur[NCLS];
    int tid = threadIdx.x;
    if (tid < NCLS) cnt[tid] = 0;
    __syncthreads();
    for (int r = tid; r < N_SUP; r += 1024) atomicAdd(&cnt[labels[r]], 1);
    __syncthreads();
    if (tid == 0) {
        int run = 0;
        for (int c = 0; c < NCLS; ++c) { sstart[c] = run; run += cnt[c]; }
    }
    __syncthreads();
    if (tid < NCLS) {
        cur[tid] = sstart[tid];
        gstart[tid] = sstart[tid];
        gcnt[tid] = cnt[tid];
        counts_f[tid] = fmaxf((float)cnt[tid], 1.0f);
    }
    __syncthreads();
    for (int r = tid; r < N_SUP; r += 1024) {
        int pos = atomicAdd(&cur[labels[r]], 1);
        rowlist[pos] = r;
    }
}

// atomic-free segment sum: block = (class, col-chunk of 256). Register accumulate.
__global__ __launch_bounds__(256) void k_gather(const __bf16* __restrict__ X,
                                                const int* __restrict__ rowlist,
                                                const int* __restrict__ gstart,
                                                const int* __restrict__ gcnt,
                                                float* __restrict__ outp) {
    int c = blockIdx.x;
    int col = blockIdx.y * 256 + threadIdx.x;
    int st = gstart[c], n = gcnt[c];
    float acc = 0.f;
    int i = 0;
    for (; i + 8 <= n; i += 8) {
        int r[8];
        #pragma unroll
        for (int j = 0; j < 8; ++j) r[j] = rowlist[st + i + j];
        float v[8];
        #pragma unroll
        for (int j = 0; j < 8; ++j) v[j] = (float)X[(size_t)r[j] * DIM + col];
        #pragma unroll
        for (int j = 0; j < 8; ++j) acc += v[j];
    }
    for (; i < n; ++i) acc += (float)X[(size_t)rowlist[st + i] * DIM + col];
    outp[(size_t)c * DIM + col] = acc;
}

// exact f32 head; tasksum recomputed as sum over classes of rawsum (exact identity)
__global__ __launch_bounds__(512) void k_head(const float* __restrict__ rawsum,
                                              const float* __restrict__ sp_w1,
                                              const float* __restrict__ sp_b1,
                                              const float* __restrict__ sp_w2,
                                              const float* __restrict__ sp_b2,
                                              float* __restrict__ headf,
                                              int* __restrict__ headi,
                                              float* __restrict__ dout) {
    __shared__ float tc[1024];
    __shared__ float h[512];
    __shared__ float a4[4];
    int tid = threadIdx.x;
    float t0 = 0.f, t1 = 0.f;
    for (int c = 0; c < NCLS; ++c) {
        t0 += rawsum[(size_t)c * DIM + tid];
        t1 += rawsum[(size_t)c * DIM + tid + 512];
    }
    tc[tid]       = t0 * (1.0f / N_SUP);
    tc[tid + 512] = t1 * (1.0f / N_SUP);
    __syncthreads();
    float acc = 0.f;
    for (int k = 0; k < 1024; ++k) acc += tc[k] * sp_w1[(size_t)k * 512 + tid];
    acc += sp_b1[tid];
    h[tid] = acc > 0.f ? acc : 0.f;
    __syncthreads();
    if (tid < 4) {
        float s = 0.f;
        for (int k = 0; k < 512; ++k) s += h[k] * sp_w2[k * 4 + tid];
        s += sp_b2[tid];
        a4[tid] = 1.0f / (1.0f + expf(-s));
    }
    __syncthreads();
    if (tid == 0) {
        int kk = 0;
        int lvl[4] = {-1, -1, -1, -1};
        for (int l = 0; l < 4; ++l)
            if (a4[l] > 0.1f) { lvl[kk] = l; kk++; }
        headi[0] = kk;
        for (int s = 0; s < 4; ++s) headi[1 + s] = lvl[s];
        for (int l = 0; l < 4; ++l) headf[l] = a4[l];
    }
    if (tid < 4) {
        dout[65536 + tid] = a4[tid];
        dout[65540 + tid] = a4[tid] > 0.1f ? a4[tid] : 0.f;
    }
}

// bf16 MFMA GEMM, m97 structure: 128x128 tile, BK=32, 4 waves 2x2,
// global_load_lds width-16 staging into linear [128][32] LDS. bf16 output.
__global__ __launch_bounds__(256) void k_gemm(const __bf16* __restrict__ A,
                                              const __bf16* __restrict__ Bt,
                                              const float* __restrict__ bias,
                                              __bf16* __restrict__ C,
                                              int M, int Nn, int K) {
    __shared__ __align__(16) __bf16 As[128 * 32];   // linear row-major [128][32]
    __shared__ __align__(16) __bf16 Bs[128 * 32];
    int tid = threadIdx.x;
    int lane = tid & 63;
    int w = tid >> 6;                 // wave 0..3
    int wr = w >> 1, wc = w & 1;
    size_t bm = (size_t)blockIdx.x * 128;
    size_t bn = (size_t)blockIdx.y * 128;
    f32x4 acc[4][4] = {};

    int srow0 = w * 16 + (lane >> 2);
    int srow1 = (w + 4) * 16 + (lane >> 2);
    int scol  = (lane & 3) * 8;
    const __bf16* ga0 = A  + (bm + srow0) * K + scol;
    const __bf16* ga1 = A  + (bm + srow1) * K + scol;
    const __bf16* gb0 = Bt + (bn + srow0) * K + scol;
    const __bf16* gb1 = Bt + (bn + srow1) * K + scol;
    __bf16* la0 = As + (size_t)w * 512;
    __bf16* la1 = As + (size_t)(w + 4) * 512;
    __bf16* lb0 = Bs + (size_t)w * 512;
    __bf16* lb1 = Bs + (size_t)(w + 4) * 512;

    int am = lane & 15;
    int kko = (lane >> 4) * 8;

    for (int k0 = 0; k0 < K; k0 += 32) {
        __syncthreads();
        GLOAD_LDS16(ga0 + k0, la0);
        GLOAD_LDS16(ga1 + k0, la1);
        GLOAD_LDS16(gb0 + k0, lb0);
        GLOAD_LDS16(gb1 + k0, lb1);
        __syncthreads();
        bf16x8 af[4], bfr[4];
        #pragma unroll
        for (int mi = 0; mi < 4; ++mi)
            af[mi] = *(const bf16x8*)(As + (wr * 64 + mi * 16 + am) * 32 + kko);
        #pragma unroll
        for (int ni = 0; ni < 4; ++ni)
            bfr[ni] = *(const bf16x8*)(Bs + (wc * 64 + ni * 16 + am) * 32 + kko);
        #pragma unroll
        for (int mi = 0; mi < 4; ++mi)
            #pragma unroll
            for (int ni = 0; ni < 4; ++ni)
                acc[mi][ni] = __builtin_amdgcn_mfma_f32_16x16x32_bf16(af[mi], bfr[ni], acc[mi][ni], 0, 0, 0);
    }
    int rbase = (lane >> 4) * 4;      // C/D: col=lane&15, row=(lane>>4)*4+reg
    #pragma unroll
    for (int mi = 0; mi < 4; ++mi) {
        size_t row = bm + wr * 64 + mi * 16 + rbase;
        #pragma unroll
        for (int ni = 0; ni < 4; ++ni) {
            int col = (int)bn + wc * 64 + ni * 16 + am;
            float bv = bias[col];
            #pragma unroll
            for (int r = 0; r < 4; ++r)
                C[(row + r) * Nn + col] = (__bf16)(acc[mi][ni][r] + bv);
        }
    }
}

__global__ __launch_bounds__(256) void k_ln_relu(const __bf16* __restrict__ hh,
                                                 const float* __restrict__ gamma,
                                                 const float* __restrict__ beta,
                                                 __bf16* __restrict__ outp) {
    __shared__ float ss[4], qq[4], mv[2];
    int row = blockIdx.x;
    int tid = threadIdx.x;
    bf16x4 v = *(const bf16x4*)(hh + (size_t)row * DIM + tid * 4);
    float x[4];
    #pragma unroll
    for (int j = 0; j < 4; ++j) x[j] = (float)v[j];
    float s = x[0] + x[1] + x[2] + x[3];
    float q = x[0] * x[0] + x[1] * x[1] + x[2] * x[2] + x[3] * x[3];
    #pragma unroll
    for (int off = 32; off > 0; off >>= 1) {
        s += __shfl_down(s, off);
        q += __shfl_down(q, off);
    }
    int w = tid >> 6;
    if ((tid & 63) == 0) { ss[w] = s; qq[w] = q; }
    __syncthreads();
    if (tid == 0) {
        float S = ss[0] + ss[1] + ss[2] + ss[3];
        float Q = qq[0] + qq[1] + qq[2] + qq[3];
        float mu = S * (1.0f / DIM);
        float var = Q * (1.0f / DIM) - mu * mu;
        mv[0] = mu;
        mv[1] = rsqrtf(var + 1e-5f);
    }
    __syncthreads();
    float mu = mv[0], rstd = mv[1];
    union { __bf16 b[4]; uint64_t u; } pk;
    #pragma unroll
    for (int j = 0; j < 4; ++j) {
        int colj = tid * 4 + j;
        float y = (x[j] - mu) * rstd * gamma[colj] + beta[colj];
        pk.b[j] = (__bf16)(y > 0.f ? y : 0.f);
    }
    *(uint64_t*)(outp + (size_t)row * DIM + tid * 4) = pk.u;
}

// fusion_input build: fi is 64 x 4160 (zero-padded beyond S=4100)
__global__ __launch_bounds__(256) void k_build_fi(const float* __restrict__ psum,
                                                  const float* __restrict__ counts_f,
                                                  const float* __restrict__ headf,
                                                  const int* __restrict__ headi,
                                                  float* __restrict__ fi) {
    int idx = blockIdx.x * 256 + threadIdx.x;
    if (idx >= 64 * 4160) return;
    int c = idx / 4160, col = idx % 4160;
    int kk = headi[0];
    float v = 0.f;
    if (col < kk * 1024) {
        int s = col >> 10, d = col & 1023;
        int l = headi[1 + s];
        v = psum[((size_t)l * NCLS + c) * DIM + d] / counts_f[c];
    } else if (col < kk * 1024 + kk) {
        int s = col - kk * 1024;
        v = headf[headi[1 + s]];
    }
    fi[idx] = v;
}

// fusion GEMM: one 64-wide K-chunk per block, split-K, atomic accumulate.
__global__ __launch_bounds__(256) void k_fuse_gemm(const float* __restrict__ Afi,
                                                   const float* __restrict__ W,
                                                   float* __restrict__ outp,
                                                   int lda, int K) {
    __shared__ float fi_lds[64][64];
    int tid = threadIdx.x;
    int tj = tid & 63, tg = tid >> 6;
    int jb = blockIdx.x;
    int k0 = blockIdx.y * 64;
    for (int i = tid; i < 64 * 64; i += 256) {
        int cc = i >> 6, kq = i & 63;
        fi_lds[cc][kq] = (k0 + kq < lda) ? Afi[(size_t)cc * lda + k0 + kq] : 0.f;
    }
    __syncthreads();
    float acc[16] = {};
    #pragma unroll 4
    for (int kq = 0; kq < 64; ++kq) {
        int kg = k0 + kq;
        float wv = (kg < K) ? W[(size_t)kg * 1024 + jb * 64 + tj] : 0.f;
        #pragma unroll
        for (int cc = 0; cc < 16; ++cc)
            acc[cc] += fi_lds[tg * 16 + cc][kq] * wv;
    }
    #pragma unroll
    for (int cc = 0; cc < 16; ++cc)
        atomicAdd(&outp[(size_t)(tg * 16 + cc) * 1024 + jb * 64 + tj], acc[cc]);
}

__global__ __launch_bounds__(256) void k_bias_relu(const float* __restrict__ pre,
                                                   const float* __restrict__ b,
                                                   float* __restrict__ outp) {
    int i = blockIdx.x * 256 + threadIdx.x;   // 65536
    int j = i & 1023;
    float v = pre[i] + b[j];
    outp[i] = v > 0.f ? v : 0.f;
}

__global__ __launch_bounds__(256) void k_final(const float* __restrict__ pre2,
                                               const float* __restrict__ fu_b2,
                                               const int* __restrict__ headi,
                                               const float* __restrict__ rawsum,
                                               const float* __restrict__ counts_f,
                                               float* __restrict__ dout) {
    int i = blockIdx.x * 256 + threadIdx.x;   // 65536
    int c = i >> 10, j = i & 1023;
    float v;
    if (headi[0] > 0) v = pre2[i] + fu_b2[j];
    else              v = rawsum[i] / counts_f[c];
    dout[i] = v;
}

extern "C" void kernel_launch(void* const* d_in, const int* in_sizes, int n_in,
                              void* d_out, int out_size, void* d_ws, size_t ws_size,
                              hipStream_t stream) {
    (void)in_sizes; (void)n_in; (void)out_size; (void)ws_size;
    const float* feat    = (const float*)d_in[0];
    const int*   labels  = (const int*)d_in[1];
    const float* sp_w1   = (const float*)d_in[2];
    const float* sp_b1   = (const float*)d_in[3];
    const float* sp_w2   = (const float*)d_in[4];
    const float* sp_b2   = (const float*)d_in[5];
    const float* lvl_emb = (const float*)d_in[6];
    const float* an_w1   = (const float*)d_in[7];
    const float* an_b1   = (const float*)d_in[8];
    const float* an_g    = (const float*)d_in[9];
    const float* an_be   = (const float*)d_in[10];
    const float* an_w2   = (const float*)d_in[11];
    const float* an_b2   = (const float*)d_in[12];
    const float* fu_w1   = (const float*)d_in[13];
    const float* fu_b1   = (const float*)d_in[14];
    const float* fu_w2   = (const float*)d_in[15];
    const float* fu_b2   = (const float*)d_in[16];
    float* dout = (float*)d_out;

    char* p = (char*)d_ws;
    auto alloc = [&](size_t b) { char* r = p; p += (b + 255) & ~(size_t)255; return r; };
    __bf16* featb = (__bf16*)alloc((size_t)N_SUP * DIM * 2);
    __bf16* w1t   = (__bf16*)alloc((size_t)NLV * DIM * DIM * 2);
    __bf16* w2t   = (__bf16*)alloc((size_t)NLV * DIM * DIM * 2);
    __bf16* hh_b  = (__bf16*)alloc((size_t)N_SUP * DIM * 2);
    __bf16* hhp   = (__bf16*)alloc((size_t)N_SUP * DIM * 2);
    __bf16* tb    = (__bf16*)alloc((size_t)N_SUP * DIM * 2);
    float*  effb1 = (float*) alloc((size_t)NLV * DIM * 4);
    float*  fi    = (float*) alloc((size_t)64 * 4160 * 4);
    float*  h1    = (float*) alloc((size_t)NCLS * DIM * 4);
    float*  rawsum  = (float*)alloc((size_t)NCLS * DIM * 4);
    float*  psum    = (float*)alloc((size_t)NLV * NCLS * DIM * 4);
    int*    rowlist = (int*)  alloc((size_t)N_SUP * 4);
    int*    gstart  = (int*)  alloc(NCLS * 4);
    int*    gcnt    = (int*)  alloc(NCLS * 4);
    float*  counts_f= (float*)alloc(NCLS * 4);
    float*  headf   = (float*)alloc(4 * 4);
    int*    headi   = (int*)  alloc(8 * 4);
    char* z0 = p;
    float*  h1pre   = (float*)alloc((size_t)NCLS * DIM * 4);
    float*  f2pre   = (float*)alloc((size_t)NCLS * DIM * 4);
    size_t zbytes = (size_t)(p - z0);
    hipMemsetAsync(z0, 0, zbytes, stream);

    k_conv_feat<<<N_SUP * DIM / 4 / 256, 256, 0, stream>>>(feat, featb);
    k_wt<<<dim3(16, 16, 8), 256, 0, stream>>>(an_w1, an_w2, w1t, w2t);
    k_eff_b1<<<16, 256, 0, stream>>>(an_w1, an_b1, lvl_emb, effb1);
    k_rowlist<<<1, 1024, 0, stream>>>(labels, rowlist, gstart, gcnt, counts_f);
    k_gather<<<dim3(NCLS, 4), 256, 0, stream>>>(featb, rowlist, gstart, gcnt, rawsum);
    k_head<<<1, 512, 0, stream>>>(rawsum, sp_w1, sp_b1, sp_w2, sp_b2, headf, headi, dout);

    for (int l = 0; l < NLV; ++l) {
        k_gemm<<<dim3(128, 8), 256, 0, stream>>>(featb, w1t + (size_t)l * DIM * DIM,
                                                 effb1 + l * DIM, hh_b, N_SUP, DIM, DIM);
        k_ln_relu<<<N_SUP, 256, 0, stream>>>(hh_b, an_g + l * DIM, an_be + l * DIM, hhp);
        k_gemm<<<dim3(128, 8), 256, 0, stream>>>(hhp, w2t + (size_t)l * DIM * DIM,
                                                 an_b2 + l * DIM, tb, N_SUP, DIM, DIM);
        k_gather<<<dim3(NCLS, 4), 256, 0, stream>>>(tb, rowlist, gstart, gcnt,
                                                    psum + (size_t)l * NCLS * DIM);
    }

    k_build_fi<<<(64 * 4160) / 256, 256, 0, stream>>>(psum, counts_f, headf, headi, fi);
    k_fuse_gemm<<<dim3(16, 65), 256, 0, stream>>>(fi, fu_w1, h1pre, 4160, 4100);
    k_bias_relu<<<NCLS * DIM / 256, 256, 0, stream>>>(h1pre, fu_b1, h1);
    k_fuse_gemm<<<dim3(16, 16), 256, 0, stream>>>(h1, fu_w2, f2pre, 1024, 1024);
    k_final<<<NCLS * DIM / 256, 256, 0, stream>>>(f2pre, fu_b2, headi, rawsum, counts_f, dout);
}

// Round 4
// 565.149 us; speedup vs baseline: 2.4255x; 1.3578x over previous
//
#include <hip/hip_runtime.h>
#include <hip/hip_bf16.h>
#include <stdint.h>

#define N_SUP 16384
#define DIM   1024
#define NLV   4
#define NCLS  64

typedef __bf16 bf16x8 __attribute__((ext_vector_type(8)));
typedef __bf16 bf16x4 __attribute__((ext_vector_type(4)));
typedef float  f32x4  __attribute__((ext_vector_type(4)));

#define GLOAD_LDS16(g, l) \
    __builtin_amdgcn_global_load_lds((const __attribute__((address_space(1))) void*)(g), \
                                     (__attribute__((address_space(3))) void*)(l), 16, 0, 0)

// ---------------- conversions ----------------
__global__ __launch_bounds__(256) void k_conv_feat(const float* __restrict__ f,
                                                   __bf16* __restrict__ o) {
    size_t i = ((size_t)blockIdx.x * 256 + threadIdx.x) * 4;
    float4 v = *(const float4*)(f + i);
    union { __bf16 b[4]; uint64_t u; } pk;
    pk.b[0] = (__bf16)v.x; pk.b[1] = (__bf16)v.y;
    pk.b[2] = (__bf16)v.z; pk.b[3] = (__bf16)v.w;
    *(uint64_t*)(o + i) = pk.u;
}

// transpose+convert an_w1[l][:1024][:] into N-major (N x K) bf16 (W2 stays f32 now)
__global__ __launch_bounds__(256) void k_wt(const float* __restrict__ an_w1,
                                            __bf16* __restrict__ w1t) {
    __shared__ float tile[64][65];
    int m = blockIdx.z;
    const float* src = an_w1 + (size_t)m * 1025 * 1024;
    __bf16* dst = w1t + (size_t)m * 1024 * 1024;
    int k0 = blockIdx.x * 64, n0 = blockIdx.y * 64;
    int j = threadIdx.x & 63, i0 = threadIdx.x >> 6;
    #pragma unroll
    for (int ii = 0; ii < 16; ++ii) {
        int i = i0 + ii * 4;
        tile[i][j] = src[(size_t)(k0 + i) * 1024 + n0 + j];
    }
    __syncthreads();
    #pragma unroll
    for (int ii = 0; ii < 16; ++ii) {
        int i = i0 + ii * 4;
        dst[(size_t)(n0 + i) * 1024 + k0 + j] = (__bf16)tile[j][i];   // dst[n][k]=src[k][n]
    }
}

// eff_b1[l][j] = an_b1[l][j] + lvl_emb[l] * an_w1[l][1024][j]
__global__ __launch_bounds__(256) void k_eff_b1(const float* __restrict__ an_w1,
                                                const float* __restrict__ an_b1,
                                                const float* __restrict__ lvl_emb,
                                                float* __restrict__ eff) {
    int i = blockIdx.x * 256 + threadIdx.x;      // 0..4095
    int l = i >> 10, j = i & 1023;
    eff[i] = an_b1[i] + lvl_emb[l] * an_w1[(size_t)l * 1025 * 1024 + (size_t)1024 * 1024 + j];
}

// build per-class row lists: counts, starts, scattered row indices. One block.
__global__ __launch_bounds__(1024) void k_rowlist(const int* __restrict__ labels,
                                                  int* __restrict__ rowlist,
                                                  int* __restrict__ gstart,
                                                  int* __restrict__ gcnt,
                                                  float* __restrict__ counts_f) {
    __shared__ int cnt[NCLS];
    __shared__ int sstart[NCLS];
    __shared__ int cur[NCLS];
    int tid = threadIdx.x;
    if (tid < NCLS) cnt[tid] = 0;
    __syncthreads();
    for (int r = tid; r < N_SUP; r += 1024) atomicAdd(&cnt[labels[r]], 1);
    __syncthreads();
    if (tid == 0) {
        int run = 0;
        for (int c = 0; c < NCLS; ++c) { sstart[c] = run; run += cnt[c]; }
    }
    __syncthreads();
    if (tid < NCLS) {
        cur[tid] = sstart[tid];
        gstart[tid] = sstart[tid];
        gcnt[tid] = cnt[tid];
        counts_f[tid] = fmaxf((float)cnt[tid], 1.0f);
    }
    __syncthreads();
    for (int r = tid; r < N_SUP; r += 1024) {
        int pos = atomicAdd(&cur[labels[r]], 1);
        rowlist[pos] = r;
    }
}

// atomic-free segment sum: block = (class, col-chunk of 256). div: divide by count.
__global__ __launch_bounds__(256) void k_gather(const __bf16* __restrict__ X,
                                                const int* __restrict__ rowlist,
                                                const int* __restrict__ gstart,
                                                const int* __restrict__ gcnt,
                                                const float* __restrict__ counts_f,
                                                float* __restrict__ outp, int div) {
    int c = blockIdx.x;
    int col = blockIdx.y * 256 + threadIdx.x;
    int st = gstart[c], n = gcnt[c];
    float acc = 0.f;
    int i = 0;
    for (; i + 8 <= n; i += 8) {
        int r[8];
        #pragma unroll
        for (int j = 0; j < 8; ++j) r[j] = rowlist[st + i + j];
        float v[8];
        #pragma unroll
        for (int j = 0; j < 8; ++j) v[j] = (float)X[(size_t)r[j] * DIM + col];
        #pragma unroll
        for (int j = 0; j < 8; ++j) acc += v[j];
    }
    for (; i < n; ++i) acc += (float)X[(size_t)rowlist[st + i] * DIM + col];
    float sc = div ? (1.0f / counts_f[c]) : 1.0f;
    outp[(size_t)c * DIM + col] = acc * sc;
}

// tc[j] = (sum_c rawsum[c][j]) / N
__global__ __launch_bounds__(256) void k_tasksum(const float* __restrict__ rawsum,
                                                 float* __restrict__ tc) {
    int j = blockIdx.x * 256 + threadIdx.x;
    float t = 0.f;
    for (int c = 0; c < NCLS; ++c) t += rawsum[(size_t)c * DIM + j];
    tc[j] = t * (1.0f / N_SUP);
}

// split-K GEMV: hpre[j] += sum_{k in chunk} tc[k]*sp_w1[k][j]
__global__ __launch_bounds__(512) void k_gemv1(const float* __restrict__ tc,
                                               const float* __restrict__ sp_w1,
                                               float* __restrict__ hpre) {
    __shared__ float tcs[64];
    int tid = threadIdx.x;
    int kb = blockIdx.x * 64;
    if (tid < 64) tcs[tid] = tc[kb + tid];
    __syncthreads();
    float acc = 0.f;
    #pragma unroll 8
    for (int k = 0; k < 64; ++k)
        acc += tcs[k] * sp_w1[(size_t)(kb + k) * 512 + tid];
    atomicAdd(&hpre[tid], acc);
}

// finish head: relu, 512x4 layer, sigmoid, mask/slots; writes acts outputs
__global__ __launch_bounds__(512) void k_head_fin(const float* __restrict__ hpre,
                                                  const float* __restrict__ sp_b1,
                                                  const float* __restrict__ sp_w2,
                                                  const float* __restrict__ sp_b2,
                                                  float* __restrict__ headf,
                                                  int* __restrict__ headi,
                                                  float* __restrict__ dout) {
    __shared__ float red[512];
    __shared__ float a4[4];
    int tid = threadIdx.x;
    float hv = hpre[tid] + sp_b1[tid];
    hv = hv > 0.f ? hv : 0.f;
    #pragma unroll
    for (int o = 0; o < 4; ++o) {
        red[tid] = hv * sp_w2[tid * 4 + o];
        __syncthreads();
        for (int st = 256; st > 0; st >>= 1) {
            if (tid < st) red[tid] += red[tid + st];
            __syncthreads();
        }
        if (tid == 0) a4[o] = 1.0f / (1.0f + expf(-(red[0] + sp_b2[o])));
        __syncthreads();
    }
    if (tid == 0) {
        int kk = 0;
        int lvl[4] = {-1, -1, -1, -1};
        for (int l = 0; l < 4; ++l)
            if (a4[l] > 0.1f) { lvl[kk] = l; kk++; }
        headi[0] = kk;
        for (int s = 0; s < 4; ++s) headi[1 + s] = lvl[s];
        for (int l = 0; l < 4; ++l) headf[l] = a4[l];
    }
    if (tid < 4) {
        dout[65536 + tid] = a4[tid];
        dout[65540 + tid] = a4[tid] > 0.1f ? a4[tid] : 0.f;
    }
}

// bf16 MFMA GEMM, m97 structure: 128x128 tile, BK=32, 4 waves 2x2,
// global_load_lds width-16 staging into linear [128][32] LDS. bf16 output.
__global__ __launch_bounds__(256) void k_gemm(const __bf16* __restrict__ A,
                                              const __bf16* __restrict__ Bt,
                                              const float* __restrict__ bias,
                                              __bf16* __restrict__ C,
                                              int M, int Nn, int K) {
    __shared__ __align__(16) __bf16 As[128 * 32];   // linear row-major [128][32]
    __shared__ __align__(16) __bf16 Bs[128 * 32];
    int tid = threadIdx.x;
    int lane = tid & 63;
    int w = tid >> 6;                 // wave 0..3
    int wr = w >> 1, wc = w & 1;
    size_t bm = (size_t)blockIdx.x * 128;
    size_t bn = (size_t)blockIdx.y * 128;
    f32x4 acc[4][4] = {};

    int srow0 = w * 16 + (lane >> 2);
    int srow1 = (w + 4) * 16 + (lane >> 2);
    int scol  = (lane & 3) * 8;
    const __bf16* ga0 = A  + (bm + srow0) * K + scol;
    const __bf16* ga1 = A  + (bm + srow1) * K + scol;
    const __bf16* gb0 = Bt + (bn + srow0) * K + scol;
    const __bf16* gb1 = Bt + (bn + srow1) * K + scol;
    __bf16* la0 = As + (size_t)w * 512;
    __bf16* la1 = As + (size_t)(w + 4) * 512;
    __bf16* lb0 = Bs + (size_t)w * 512;
    __bf16* lb1 = Bs + (size_t)(w + 4) * 512;

    int am = lane & 15;
    int kko = (lane >> 4) * 8;

    for (int k0 = 0; k0 < K; k0 += 32) {
        __syncthreads();
        GLOAD_LDS16(ga0 + k0, la0);
        GLOAD_LDS16(ga1 + k0, la1);
        GLOAD_LDS16(gb0 + k0, lb0);
        GLOAD_LDS16(gb1 + k0, lb1);
        __syncthreads();
        bf16x8 af[4], bfr[4];
        #pragma unroll
        for (int mi = 0; mi < 4; ++mi)
            af[mi] = *(const bf16x8*)(As + (wr * 64 + mi * 16 + am) * 32 + kko);
        #pragma unroll
        for (int ni = 0; ni < 4; ++ni)
            bfr[ni] = *(const bf16x8*)(Bs + (wc * 64 + ni * 16 + am) * 32 + kko);
        #pragma unroll
        for (int mi = 0; mi < 4; ++mi)
            #pragma unroll
            for (int ni = 0; ni < 4; ++ni)
                acc[mi][ni] = __builtin_amdgcn_mfma_f32_16x16x32_bf16(af[mi], bfr[ni], acc[mi][ni], 0, 0, 0);
    }
    int rbase = (lane >> 4) * 4;      // C/D: col=lane&15, row=(lane>>4)*4+reg
    #pragma unroll
    for (int mi = 0; mi < 4; ++mi) {
        size_t row = bm + wr * 64 + mi * 16 + rbase;
        #pragma unroll
        for (int ni = 0; ni < 4; ++ni) {
            int col = (int)bn + wc * 64 + ni * 16 + am;
            float bv = bias[col];
            #pragma unroll
            for (int r = 0; r < 4; ++r)
                C[(row + r) * Nn + col] = (__bf16)(acc[mi][ni][r] + bv);
        }
    }
}

__global__ __launch_bounds__(256) void k_ln_relu(const __bf16* __restrict__ hh,
                                                 const float* __restrict__ gamma,
                                                 const float* __restrict__ beta,
                                                 __bf16* __restrict__ outp) {
    __shared__ float ss[4], qq[4], mv[2];
    int row = blockIdx.x;
    int tid = threadIdx.x;
    bf16x4 v = *(const bf16x4*)(hh + (size_t)row * DIM + tid * 4);
    float x[4];
    #pragma unroll
    for (int j = 0; j < 4; ++j) x[j] = (float)v[j];
    float s = x[0] + x[1] + x[2] + x[3];
    float q = x[0] * x[0] + x[1] * x[1] + x[2] * x[2] + x[3] * x[3];
    #pragma unroll
    for (int off = 32; off > 0; off >>= 1) {
        s += __shfl_down(s, off);
        q += __shfl_down(q, off);
    }
    int w = tid >> 6;
    if ((tid & 63) == 0) { ss[w] = s; qq[w] = q; }
    __syncthreads();
    if (tid == 0) {
        float S = ss[0] + ss[1] + ss[2] + ss[3];
        float Q = qq[0] + qq[1] + qq[2] + qq[3];
        float mu = S * (1.0f / DIM);
        float var = Q * (1.0f / DIM) - mu * mu;
        mv[0] = mu;
        mv[1] = rsqrtf(var + 1e-5f);
    }
    __syncthreads();
    float mu = mv[0], rstd = mv[1];
    union { __bf16 b[4]; uint64_t u; } pk;
    #pragma unroll
    for (int j = 0; j < 4; ++j) {
        int colj = tid * 4 + j;
        float y = (x[j] - mu) * rstd * gamma[colj] + beta[colj];
        pk.b[j] = (__bf16)(y > 0.f ? y : 0.f);
    }
    *(uint64_t*)(outp + (size_t)row * DIM + tid * 4) = pk.u;
}

// fusion_input build: packed part = proto_pre[l][c][d] + b2[l][d] (0 if empty class)
__global__ __launch_bounds__(256) void k_build_fi(const float* __restrict__ proto_pre,
                                                  const float* __restrict__ an_b2,
                                                  const int* __restrict__ gcnt,
                                                  const float* __restrict__ headf,
                                                  const int* __restrict__ headi,
                                                  float* __restrict__ fi) {
    int idx = blockIdx.x * 256 + threadIdx.x;
    if (idx >= 64 * 4160) return;
    int c = idx / 4160, col = idx % 4160;
    int kk = headi[0];
    float v = 0.f;
    if (col < kk * 1024) {
        int s = col >> 10, d = col & 1023;
        int l = headi[1 + s];
        if (gcnt[c] > 0)
            v = proto_pre[((size_t)l * NCLS + c) * DIM + d] + an_b2[(size_t)l * DIM + d];
    } else if (col < kk * 1024 + kk) {
        int s = col - kk * 1024;
        v = headf[headi[1 + s]];
    }
    fi[idx] = v;
}

// f32 GEMM (64 x 1024 out): one 64-wide K-chunk per block, split-K, atomic accumulate.
__global__ __launch_bounds__(256) void k_fuse_gemm(const float* __restrict__ Afi,
                                                   const float* __restrict__ W,
                                                   float* __restrict__ outp,
                                                   int lda, int K) {
    __shared__ float fi_lds[64][64];
    int tid = threadIdx.x;
    int tj = tid & 63, tg = tid >> 6;
    int jb = blockIdx.x;
    int k0 = blockIdx.y * 64;
    for (int i = tid; i < 64 * 64; i += 256) {
        int cc = i >> 6, kq = i & 63;
        fi_lds[cc][kq] = (k0 + kq < lda) ? Afi[(size_t)cc * lda + k0 + kq] : 0.f;
    }
    __syncthreads();
    float acc[16] = {};
    #pragma unroll 4
    for (int kq = 0; kq < 64; ++kq) {
        int kg = k0 + kq;
        float wv = (kg < K) ? W[(size_t)kg * 1024 + jb * 64 + tj] : 0.f;
        #pragma unroll
        for (int cc = 0; cc < 16; ++cc)
            acc[cc] += fi_lds[tg * 16 + cc][kq] * wv;
    }
    #pragma unroll
    for (int cc = 0; cc < 16; ++cc)
        atomicAdd(&outp[(size_t)(tg * 16 + cc) * 1024 + jb * 64 + tj], acc[cc]);
}

__global__ __launch_bounds__(256) void k_bias_relu(const float* __restrict__ pre,
                                                   const float* __restrict__ b,
                                                   float* __restrict__ outp) {
    int i = blockIdx.x * 256 + threadIdx.x;   // 65536
    int j = i & 1023;
    float v = pre[i] + b[j];
    outp[i] = v > 0.f ? v : 0.f;
}

__global__ __launch_bounds__(256) void k_final(const float* __restrict__ pre2,
                                               const float* __restrict__ fu_b2,
                                               const int* __restrict__ headi,
                                               const float* __restrict__ rawsum,
                                               const float* __restrict__ counts_f,
                                               float* __restrict__ dout) {
    int i = blockIdx.x * 256 + threadIdx.x;   // 65536
    int c = i >> 10, j = i & 1023;
    float v;
    if (headi[0] > 0) v = pre2[i] + fu_b2[j];
    else              v = rawsum[i] / counts_f[c];
    dout[i] = v;
}

extern "C" void kernel_launch(void* const* d_in, const int* in_sizes, int n_in,
                              void* d_out, int out_size, void* d_ws, size_t ws_size,
                              hipStream_t stream) {
    (void)in_sizes; (void)n_in; (void)out_size; (void)ws_size;
    const float* feat    = (const float*)d_in[0];
    const int*   labels  = (const int*)d_in[1];
    const float* sp_w1   = (const float*)d_in[2];
    const float* sp_b1   = (const float*)d_in[3];
    const float* sp_w2   = (const float*)d_in[4];
    const float* sp_b2   = (const float*)d_in[5];
    const float* lvl_emb = (const float*)d_in[6];
    const float* an_w1   = (const float*)d_in[7];
    const float* an_b1   = (const float*)d_in[8];
    const float* an_g    = (const float*)d_in[9];
    const float* an_be   = (const float*)d_in[10];
    const float* an_w2   = (const float*)d_in[11];
    const float* an_b2   = (const float*)d_in[12];
    const float* fu_w1   = (const float*)d_in[13];
    const float* fu_b1   = (const float*)d_in[14];
    const float* fu_w2   = (const float*)d_in[15];
    const float* fu_b2   = (const float*)d_in[16];
    float* dout = (float*)d_out;

    char* p = (char*)d_ws;
    auto alloc = [&](size_t b) { char* r = p; p += (b + 255) & ~(size_t)255; return r; };
    __bf16* featb = (__bf16*)alloc((size_t)N_SUP * DIM * 2);
    __bf16* w1t   = (__bf16*)alloc((size_t)NLV * DIM * DIM * 2);
    __bf16* hh_b  = (__bf16*)alloc((size_t)N_SUP * DIM * 2);
    __bf16* hhp   = (__bf16*)alloc((size_t)N_SUP * DIM * 2);
    float*  effb1 = (float*) alloc((size_t)NLV * DIM * 4);
    float*  fi    = (float*) alloc((size_t)64 * 4160 * 4);
    float*  h1    = (float*) alloc((size_t)NCLS * DIM * 4);
    float*  rawsum  = (float*)alloc((size_t)NCLS * DIM * 4);
    float*  gsum    = (float*)alloc((size_t)NCLS * DIM * 4);
    float*  tc      = (float*)alloc(DIM * 4);
    int*    rowlist = (int*)  alloc((size_t)N_SUP * 4);
    int*    gstart  = (int*)  alloc(NCLS * 4);
    int*    gcnt    = (int*)  alloc(NCLS * 4);
    float*  counts_f= (float*)alloc(NCLS * 4);
    float*  headf   = (float*)alloc(4 * 4);
    int*    headi   = (int*)  alloc(8 * 4);
    char* z0 = p;
    float*  proto_pre = (float*)alloc((size_t)NLV * NCLS * DIM * 4);
    float*  h1pre   = (float*)alloc((size_t)NCLS * DIM * 4);
    float*  f2pre   = (float*)alloc((size_t)NCLS * DIM * 4);
    float*  hpre    = (float*)alloc(512 * 4);
    size_t zbytes = (size_t)(p - z0);
    hipMemsetAsync(z0, 0, zbytes, stream);

    k_conv_feat<<<N_SUP * DIM / 4 / 256, 256, 0, stream>>>(feat, featb);
    k_wt<<<dim3(16, 16, 4), 256, 0, stream>>>(an_w1, w1t);
    k_eff_b1<<<16, 256, 0, stream>>>(an_w1, an_b1, lvl_emb, effb1);
    k_rowlist<<<1, 1024, 0, stream>>>(labels, rowlist, gstart, gcnt, counts_f);
    k_gather<<<dim3(NCLS, 4), 256, 0, stream>>>(featb, rowlist, gstart, gcnt, counts_f, rawsum, 0);
    k_tasksum<<<4, 256, 0, stream>>>(rawsum, tc);
    k_gemv1<<<16, 512, 0, stream>>>(tc, sp_w1, hpre);
    k_head_fin<<<1, 512, 0, stream>>>(hpre, sp_b1, sp_w2, sp_b2, headf, headi, dout);

    for (int l = 0; l < NLV; ++l) {
        k_gemm<<<dim3(128, 8), 256, 0, stream>>>(featb, w1t + (size_t)l * DIM * DIM,
                                                 effb1 + l * DIM, hh_b, N_SUP, DIM, DIM);
        k_ln_relu<<<N_SUP, 256, 0, stream>>>(hh_b, an_g + l * DIM, an_be + l * DIM, hhp);
        k_gather<<<dim3(NCLS, 4), 256, 0, stream>>>(hhp, rowlist, gstart, gcnt, counts_f, gsum, 1);
        k_fuse_gemm<<<dim3(16, 16), 256, 0, stream>>>(gsum, an_w2 + (size_t)l * DIM * DIM,
                                                      proto_pre + (size_t)l * NCLS * DIM, 1024, 1024);
    }

    k_build_fi<<<(64 * 4160) / 256, 256, 0, stream>>>(proto_pre, an_b2, gcnt, headf, headi, fi);
    k_fuse_gemm<<<dim3(16, 65), 256, 0, stream>>>(fi, fu_w1, h1pre, 4160, 4100);
    k_bias_relu<<<NCLS * DIM / 256, 256, 0, stream>>>(h1pre, fu_b1, h1);
    k_fuse_gemm<<<dim3(16, 16), 256, 0, stream>>>(h1, fu_w2, f2pre, 1024, 1024);
    k_final<<<NCLS * DIM / 256, 256, 0, stream>>>(f2pre, fu_b2, headi, rawsum, counts_f, dout);
}

// Round 5
// 414.216 us; speedup vs baseline: 3.3093x; 1.3644x over previous
//
#include <hip/hip_runtime.h>
#include <hip/hip_bf16.h>
#include <stdint.h>

#define N_SUP 16384
#define DIM   1024
#define NLV   4
#define NCLS  64
#define NFUSE 4096          // 4 levels x 1024

typedef __bf16 bf16x8 __attribute__((ext_vector_type(8)));
typedef __bf16 bf16x4 __attribute__((ext_vector_type(4)));
typedef float  f32x4  __attribute__((ext_vector_type(4)));

#define GLOAD_LDS16(g, l) \
    __builtin_amdgcn_global_load_lds((const __attribute__((address_space(1))) void*)(g), \
                                     (__attribute__((address_space(3))) void*)(l), 16, 0, 0)

// ---------------- conversions ----------------
__global__ __launch_bounds__(256) void k_conv_feat(const float* __restrict__ f,
                                                   __bf16* __restrict__ o) {
    size_t i = ((size_t)blockIdx.x * 256 + threadIdx.x) * 4;
    float4 v = *(const float4*)(f + i);
    union { __bf16 b[4]; uint64_t u; } pk;
    pk.b[0] = (__bf16)v.x; pk.b[1] = (__bf16)v.y;
    pk.b[2] = (__bf16)v.z; pk.b[3] = (__bf16)v.w;
    *(uint64_t*)(o + i) = pk.u;
}

// transpose+convert an_w1[l][:1024][:] into N-major (N x K) bf16
__global__ __launch_bounds__(256) void k_wt(const float* __restrict__ an_w1,
                                            __bf16* __restrict__ w1t) {
    __shared__ float tile[64][65];
    int m = blockIdx.z;
    const float* src = an_w1 + (size_t)m * 1025 * 1024;
    __bf16* dst = w1t + (size_t)m * 1024 * 1024;
    int k0 = blockIdx.x * 64, n0 = blockIdx.y * 64;
    int j = threadIdx.x & 63, i0 = threadIdx.x >> 6;
    #pragma unroll
    for (int ii = 0; ii < 16; ++ii) {
        int i = i0 + ii * 4;
        tile[i][j] = src[(size_t)(k0 + i) * 1024 + n0 + j];
    }
    __syncthreads();
    #pragma unroll
    for (int ii = 0; ii < 16; ++ii) {
        int i = i0 + ii * 4;
        dst[(size_t)(n0 + i) * 1024 + k0 + j] = (__bf16)tile[j][i];
    }
}

// eff_b1[l][j] = an_b1[l][j] + lvl_emb[l] * an_w1[l][1024][j]
__global__ __launch_bounds__(256) void k_eff_b1(const float* __restrict__ an_w1,
                                                const float* __restrict__ an_b1,
                                                const float* __restrict__ lvl_emb,
                                                float* __restrict__ eff) {
    int i = blockIdx.x * 256 + threadIdx.x;      // 0..4095
    int l = i >> 10, j = i & 1023;
    eff[i] = an_b1[i] + lvl_emb[l] * an_w1[(size_t)l * 1025 * 1024 + (size_t)1024 * 1024 + j];
}

// build per-class row lists
__global__ __launch_bounds__(1024) void k_rowlist(const int* __restrict__ labels,
                                                  int* __restrict__ rowlist,
                                                  int* __restrict__ gstart,
                                                  int* __restrict__ gcnt,
                                                  float* __restrict__ counts_f) {
    __shared__ int cnt[NCLS];
    __shared__ int sstart[NCLS];
    __shared__ int cur[NCLS];
    int tid = threadIdx.x;
    if (tid < NCLS) cnt[tid] = 0;
    __syncthreads();
    for (int r = tid; r < N_SUP; r += 1024) atomicAdd(&cnt[labels[r]], 1);
    __syncthreads();
    if (tid == 0) {
        int run = 0;
        for (int c = 0; c < NCLS; ++c) { sstart[c] = run; run += cnt[c]; }
    }
    __syncthreads();
    if (tid < NCLS) {
        cur[tid] = sstart[tid];
        gstart[tid] = sstart[tid];
        gcnt[tid] = cnt[tid];
        counts_f[tid] = fmaxf((float)cnt[tid], 1.0f);
    }
    __syncthreads();
    for (int r = tid; r < N_SUP; r += 1024) {
        int pos = atomicAdd(&cur[labels[r]], 1);
        rowlist[pos] = r;
    }
}

// atomic-free segment sum; ld = row stride of X; div: divide by count
__global__ __launch_bounds__(256) void k_gather(const __bf16* __restrict__ X, int ld,
                                                const int* __restrict__ rowlist,
                                                const int* __restrict__ gstart,
                                                const int* __restrict__ gcnt,
                                                const float* __restrict__ counts_f,
                                                float* __restrict__ outp, int div) {
    int c = blockIdx.x;
    int col = blockIdx.y * 256 + threadIdx.x;
    int st = gstart[c], n = gcnt[c];
    float acc = 0.f;
    int i = 0;
    for (; i + 8 <= n; i += 8) {
        int r[8];
        #pragma unroll
        for (int j = 0; j < 8; ++j) r[j] = rowlist[st + i + j];
        float v[8];
        #pragma unroll
        for (int j = 0; j < 8; ++j) v[j] = (float)X[(size_t)r[j] * ld + col];
        #pragma unroll
        for (int j = 0; j < 8; ++j) acc += v[j];
    }
    for (; i < n; ++i) acc += (float)X[(size_t)rowlist[st + i] * ld + col];
    float sc = div ? (1.0f / counts_f[c]) : 1.0f;
    outp[(size_t)c * ld + col] = acc * sc;
}

// tc[j] = (sum_c rawsum[c][j]) / N
__global__ __launch_bounds__(256) void k_tasksum(const float* __restrict__ rawsum,
                                                 float* __restrict__ tc) {
    int j = blockIdx.x * 256 + threadIdx.x;
    float t = 0.f;
    for (int c = 0; c < NCLS; ++c) t += rawsum[(size_t)c * DIM + j];
    tc[j] = t * (1.0f / N_SUP);
}

__global__ __launch_bounds__(512) void k_gemv1(const float* __restrict__ tc,
                                               const float* __restrict__ sp_w1,
                                               float* __restrict__ hpre) {
    __shared__ float tcs[64];
    int tid = threadIdx.x;
    int kb = blockIdx.x * 64;
    if (tid < 64) tcs[tid] = tc[kb + tid];
    __syncthreads();
    float acc = 0.f;
    #pragma unroll 8
    for (int k = 0; k < 64; ++k)
        acc += tcs[k] * sp_w1[(size_t)(kb + k) * 512 + tid];
    atomicAdd(&hpre[tid], acc);
}

__global__ __launch_bounds__(512) void k_head_fin(const float* __restrict__ hpre,
                                                  const float* __restrict__ sp_b1,
                                                  const float* __restrict__ sp_w2,
                                                  const float* __restrict__ sp_b2,
                                                  float* __restrict__ headf,
                                                  int* __restrict__ headi,
                                                  float* __restrict__ dout) {
    __shared__ float red[512];
    __shared__ float a4[4];
    int tid = threadIdx.x;
    float hv = hpre[tid] + sp_b1[tid];
    hv = hv > 0.f ? hv : 0.f;
    #pragma unroll
    for (int o = 0; o < 4; ++o) {
        red[tid] = hv * sp_w2[tid * 4 + o];
        __syncthreads();
        for (int st = 256; st > 0; st >>= 1) {
            if (tid < st) red[tid] += red[tid + st];
            __syncthreads();
        }
        if (tid == 0) a4[o] = 1.0f / (1.0f + expf(-(red[0] + sp_b2[o])));
        __syncthreads();
    }
    if (tid == 0) {
        int kk = 0;
        int lvl[4] = {-1, -1, -1, -1};
        for (int l = 0; l < 4; ++l)
            if (a4[l] > 0.1f) { lvl[kk] = l; kk++; }
        headi[0] = kk;
        for (int s = 0; s < 4; ++s) headi[1 + s] = lvl[s];
        for (int l = 0; l < 4; ++l) headf[l] = a4[l];
    }
    if (tid < 4) {
        dout[65536 + tid] = a4[tid];
        dout[65540 + tid] = a4[tid] > 0.1f ? a4[tid] : 0.f;
    }
}

// ==================== 256x256 8-phase bf16 MFMA GEMM ====================
// C[16384][4096] = A[16384][1024] @ Bt[4096][1024]^T + bias, bf16 out.
// 8 waves (2M x 4N), BK=64, double-buffered 128KB LDS, swizzled ds_read,
// counted vmcnt(4) once per K-tile (stage t+1 during tile t), setprio(1) on MFMA.
__global__ __launch_bounds__(512, 2) void k_gemm256(const __bf16* __restrict__ A,
                                                    const __bf16* __restrict__ Bt,
                                                    const float* __restrict__ bias,
                                                    __bf16* __restrict__ C,
                                                    int K, int Nn, int NT) {
    __shared__ __bf16 lds[65536];   // [buf][A|B][half][128][64] : 2*2*2*128*64*2B = 128KiB
    const int tid = threadIdx.x;
    const int w   = tid >> 6;       // wave 0..7
    const int l   = tid & 63;
    const int wr  = w >> 2;         // 0..1 (M)
    const int wc  = w & 3;          // 0..3 (N)
    const int am  = l & 15;
    const int kg  = l >> 4;         // 0..3
    const size_t bm = (size_t)blockIdx.x * 256;
    const size_t bn = (size_t)blockIdx.y * 256;

    // staging: half = 128x64 bf16 = 16KB = 2 passes x (512thr x 16B)
    // linear LDS dest; SOURCE col pre-swizzled by the involution col ^= (row&7)*8
    const int srow = w * 8 + (l >> 3);             // row within 64-row pass
    const int scol = ((l & 7) ^ (l >> 3)) * 8;     // pre-swizzled col (elems)
    const __bf16* gA[2][2]; const __bf16* gB[2][2];
    #pragma unroll
    for (int h = 0; h < 2; ++h)
        #pragma unroll
        for (int p = 0; p < 2; ++p) {
            gA[h][p] = A  + (bm + h * 128 + p * 64 + srow) * (size_t)K + scol;
            gB[h][p] = Bt + (bn + h * 128 + p * 64 + srow) * (size_t)K + scol;
        }

    f32x4 acc[8][4] = {};

    // prologue: stage tile 0 into buf0 (8 loads/thread-wave)
    #pragma unroll
    for (int h = 0; h < 2; ++h)
        #pragma unroll
        for (int p = 0; p < 2; ++p) {
            GLOAD_LDS16(gA[h][p], lds + h * 8192 + p * 4096 + w * 512);
            GLOAD_LDS16(gB[h][p], lds + 16384 + h * 8192 + p * 4096 + w * 512);
        }

    const int swz = (am & 7) * 8;   // read-side swizzle constant (elems)

    for (int t = 0; t < NT; ++t) {
        const int cb = (t & 1) * 32768;
        const int nb = cb ^ 32768;
        const int tn = (t + 1) * 64;
        const bool more = (t + 1 < NT);
        #pragma unroll
        for (int q = 0; q < 4; ++q) {
            // ---- stage slice of tile t+1 into the other buffer ----
            if (q == 0) {
                if (more) {
                    GLOAD_LDS16(gA[0][0] + tn, lds + nb + 0 * 4096 + w * 512);
                    GLOAD_LDS16(gA[0][1] + tn, lds + nb + 1 * 4096 + w * 512);
                    GLOAD_LDS16(gA[1][0] + tn, lds + nb + 8192 + 0 * 4096 + w * 512);
                    GLOAD_LDS16(gA[1][1] + tn, lds + nb + 8192 + 1 * 4096 + w * 512);
                    asm volatile("s_waitcnt vmcnt(4)" ::: "memory");  // tile t fully resident
                } else {
                    asm volatile("s_waitcnt vmcnt(0)" ::: "memory");
                }
                asm volatile("s_barrier" ::: "memory");               // cross-wave visibility
            } else if (q == 1) {
                if (more) {
                    GLOAD_LDS16(gB[0][0] + tn, lds + nb + 16384 + 0 * 4096 + w * 512);
                    GLOAD_LDS16(gB[0][1] + tn, lds + nb + 16384 + 1 * 4096 + w * 512);
                }
            } else if (q == 2) {
                if (more) {
                    GLOAD_LDS16(gB[1][0] + tn, lds + nb + 16384 + 8192 + 0 * 4096 + w * 512);
                    GLOAD_LDS16(gB[1][1] + tn, lds + nb + 16384 + 8192 + 1 * 4096 + w * 512);
                }
            }
            // ---- ds_read this quadrant's fragments (swizzled) ----
            const int qm = q >> 1, qn = q & 1;
            bf16x8 af[4][2], bfr[2][2];
            #pragma unroll
            for (int i = 0; i < 4; ++i) {
                const int rh = (qm * 4 + i) * 16 + am;
                #pragma unroll
                for (int kk = 0; kk < 2; ++kk)
                    af[i][kk] = *(const bf16x8*)(lds + cb + wr * 8192 + rh * 64
                                                 + ((kk * 32 + kg * 8) ^ swz));
            }
            #pragma unroll
            for (int j = 0; j < 2; ++j) {
                const int rb = (wc & 1) * 64 + (qn * 2 + j) * 16 + am;
                #pragma unroll
                for (int kk = 0; kk < 2; ++kk)
                    bfr[j][kk] = *(const bf16x8*)(lds + cb + 16384 + (wc >> 1) * 8192 + rb * 64
                                                  + ((kk * 32 + kg * 8) ^ swz));
            }
            if (q != 0) asm volatile("s_barrier" ::: "memory");
            __builtin_amdgcn_s_setprio(1);
            #pragma unroll
            for (int i = 0; i < 4; ++i)
                #pragma unroll
                for (int j = 0; j < 2; ++j)
                    #pragma unroll
                    for (int kk = 0; kk < 2; ++kk)
                        acc[qm * 4 + i][qn * 2 + j] = __builtin_amdgcn_mfma_f32_16x16x32_bf16(
                            af[i][kk], bfr[j][kk], acc[qm * 4 + i][qn * 2 + j], 0, 0, 0);
            __builtin_amdgcn_s_setprio(0);
            asm volatile("s_barrier" ::: "memory");
        }
    }

    const int rbase = kg * 4;    // C/D: col=lane&15, row=(lane>>4)*4+reg
    #pragma unroll
    for (int m = 0; m < 8; ++m) {
        const size_t row = bm + wr * 128 + m * 16 + rbase;
        #pragma unroll
        for (int n = 0; n < 4; ++n) {
            const int col = (int)bn + wc * 64 + n * 16 + am;
            const float bv = bias[col];
            #pragma unroll
            for (int r = 0; r < 4; ++r)
                C[(row + r) * (size_t)Nn + col] = (__bf16)(acc[m][n][r] + bv);
        }
    }
}

// LN+ReLU in-place on hh[16384][4096], block = (row, level)
__global__ __launch_bounds__(256) void k_ln_relu(__bf16* __restrict__ hh,
                                                 const float* __restrict__ an_g,
                                                 const float* __restrict__ an_be) {
    __shared__ float ss[4], qq[4], mv[2];
    int row = blockIdx.x, lv = blockIdx.y;
    int tid = threadIdx.x;
    size_t base = (size_t)row * NFUSE + lv * 1024;
    const float* gamma = an_g + lv * 1024;
    const float* beta  = an_be + lv * 1024;
    bf16x4 v = *(const bf16x4*)(hh + base + tid * 4);
    float x[4];
    #pragma unroll
    for (int j = 0; j < 4; ++j) x[j] = (float)v[j];
    float s = x[0] + x[1] + x[2] + x[3];
    float q = x[0] * x[0] + x[1] * x[1] + x[2] * x[2] + x[3] * x[3];
    #pragma unroll
    for (int off = 32; off > 0; off >>= 1) {
        s += __shfl_down(s, off);
        q += __shfl_down(q, off);
    }
    int w = tid >> 6;
    if ((tid & 63) == 0) { ss[w] = s; qq[w] = q; }
    __syncthreads();
    if (tid == 0) {
        float S = ss[0] + ss[1] + ss[2] + ss[3];
        float Q = qq[0] + qq[1] + qq[2] + qq[3];
        float mu = S * (1.0f / DIM);
        float var = Q * (1.0f / DIM) - mu * mu;
        mv[0] = mu;
        mv[1] = rsqrtf(var + 1e-5f);
    }
    __syncthreads();
    float mu = mv[0], rstd = mv[1];
    union { __bf16 b[4]; uint64_t u; } pk;
    #pragma unroll
    for (int j = 0; j < 4; ++j) {
        int colj = tid * 4 + j;
        float y = (x[j] - mu) * rstd * gamma[colj] + beta[colj];
        pk.b[j] = (__bf16)(y > 0.f ? y : 0.f);
    }
    *(uint64_t*)(hh + base + tid * 4) = pk.u;
}

// fusion_input build: packed part = proto_pre[l][c][d] + b2[l][d] (0 if empty class)
__global__ __launch_bounds__(256) void k_build_fi(const float* __restrict__ proto_pre,
                                                  const float* __restrict__ an_b2,
                                                  const int* __restrict__ gcnt,
                                                  const float* __restrict__ headf,
                                                  const int* __restrict__ headi,
                                                  float* __restrict__ fi) {
    int idx = blockIdx.x * 256 + threadIdx.x;
    if (idx >= 64 * 4160) return;
    int c = idx / 4160, col = idx % 4160;
    int kk = headi[0];
    float v = 0.f;
    if (col < kk * 1024) {
        int s = col >> 10, d = col & 1023;
        int l = headi[1 + s];
        if (gcnt[c] > 0)
            v = proto_pre[((size_t)l * NCLS + c) * DIM + d] + an_b2[(size_t)l * DIM + d];
    } else if (col < kk * 1024 + kk) {
        int s = col - kk * 1024;
        v = headf[headi[1 + s]];
    }
    fi[idx] = v;
}

// f32 split-K GEMM (64 x 1024 out), z-strided variant, atomic accumulate
__global__ __launch_bounds__(256) void k_fuse_gemm(const float* __restrict__ Abase, int lda, int az,
                                                   const float* __restrict__ Wbase, int wz,
                                                   float* __restrict__ outbase, int oz,
                                                   int K) {
    const float* Afi = Abase + (size_t)blockIdx.z * az;
    const float* W   = Wbase + (size_t)blockIdx.z * wz;
    float* outp      = outbase + (size_t)blockIdx.z * oz;
    __shared__ float fi_lds[64][64];
    int tid = threadIdx.x;
    int tj = tid & 63, tg = tid >> 6;
    int jb = blockIdx.x;
    int k0 = blockIdx.y * 64;
    for (int i = tid; i < 64 * 64; i += 256) {
        int cc = i >> 6, kq = i & 63;
        fi_lds[cc][kq] = (k0 + kq < lda) ? Afi[(size_t)cc * lda + k0 + kq] : 0.f;
    }
    __syncthreads();
    float acc[16] = {};
    #pragma unroll 4
    for (int kq = 0; kq < 64; ++kq) {
        int kg = k0 + kq;
        float wv = (kg < K) ? W[(size_t)kg * 1024 + jb * 64 + tj] : 0.f;
        #pragma unroll
        for (int cc = 0; cc < 16; ++cc)
            acc[cc] += fi_lds[tg * 16 + cc][kq] * wv;
    }
    #pragma unroll
    for (int cc = 0; cc < 16; ++cc)
        atomicAdd(&outp[(size_t)(tg * 16 + cc) * 1024 + jb * 64 + tj], acc[cc]);
}

__global__ __launch_bounds__(256) void k_bias_relu(const float* __restrict__ pre,
                                                   const float* __restrict__ b,
                                                   float* __restrict__ outp) {
    int i = blockIdx.x * 256 + threadIdx.x;   // 65536
    int j = i & 1023;
    float v = pre[i] + b[j];
    outp[i] = v > 0.f ? v : 0.f;
}

__global__ __launch_bounds__(256) void k_final(const float* __restrict__ pre2,
                                               const float* __restrict__ fu_b2,
                                               const int* __restrict__ headi,
                                               const float* __restrict__ rawsum,
                                               const float* __restrict__ counts_f,
                                               float* __restrict__ dout) {
    int i = blockIdx.x * 256 + threadIdx.x;   // 65536
    int c = i >> 10, j = i & 1023;
    float v;
    if (headi[0] > 0) v = pre2[i] + fu_b2[j];
    else              v = rawsum[i] / counts_f[c];
    dout[i] = v;
}

extern "C" void kernel_launch(void* const* d_in, const int* in_sizes, int n_in,
                              void* d_out, int out_size, void* d_ws, size_t ws_size,
                              hipStream_t stream) {
    (void)in_sizes; (void)n_in; (void)out_size; (void)ws_size;
    const float* feat    = (const float*)d_in[0];
    const int*   labels  = (const int*)d_in[1];
    const float* sp_w1   = (const float*)d_in[2];
    const float* sp_b1   = (const float*)d_in[3];
    const float* sp_w2   = (const float*)d_in[4];
    const float* sp_b2   = (const float*)d_in[5];
    const float* lvl_emb = (const float*)d_in[6];
    const float* an_w1   = (const float*)d_in[7];
    const float* an_b1   = (const float*)d_in[8];
    const float* an_g    = (const float*)d_in[9];
    const float* an_be   = (const float*)d_in[10];
    const float* an_w2   = (const float*)d_in[11];
    const float* an_b2   = (const float*)d_in[12];
    const float* fu_w1   = (const float*)d_in[13];
    const float* fu_b1   = (const float*)d_in[14];
    const float* fu_w2   = (const float*)d_in[15];
    const float* fu_b2   = (const float*)d_in[16];
    float* dout = (float*)d_out;

    char* p = (char*)d_ws;
    auto alloc = [&](size_t b) { char* r = p; p += (b + 255) & ~(size_t)255; return r; };
    __bf16* featb = (__bf16*)alloc((size_t)N_SUP * DIM * 2);
    __bf16* w1t   = (__bf16*)alloc((size_t)NLV * DIM * DIM * 2);
    __bf16* hh    = (__bf16*)alloc((size_t)N_SUP * NFUSE * 2);   // fused, LN in-place
    float*  effb1 = (float*) alloc((size_t)NLV * DIM * 4);
    float*  fi    = (float*) alloc((size_t)64 * 4160 * 4);
    float*  h1    = (float*) alloc((size_t)NCLS * DIM * 4);
    float*  rawsum  = (float*)alloc((size_t)NCLS * DIM * 4);
    float*  gsum    = (float*)alloc((size_t)NCLS * NFUSE * 4);
    float*  tc      = (float*)alloc(DIM * 4);
    int*    rowlist = (int*)  alloc((size_t)N_SUP * 4);
    int*    gstart  = (int*)  alloc(NCLS * 4);
    int*    gcnt    = (int*)  alloc(NCLS * 4);
    float*  counts_f= (float*)alloc(NCLS * 4);
    float*  headf   = (float*)alloc(4 * 4);
    int*    headi   = (int*)  alloc(8 * 4);
    char* z0 = p;
    float*  proto_pre = (float*)alloc((size_t)NLV * NCLS * DIM * 4);
    float*  h1pre   = (float*)alloc((size_t)NCLS * DIM * 4);
    float*  f2pre   = (float*)alloc((size_t)NCLS * DIM * 4);
    float*  hpre    = (float*)alloc(512 * 4);
    size_t zbytes = (size_t)(p - z0);
    hipMemsetAsync(z0, 0, zbytes, stream);

    k_conv_feat<<<N_SUP * DIM / 4 / 256, 256, 0, stream>>>(feat, featb);
    k_wt<<<dim3(16, 16, 4), 256, 0, stream>>>(an_w1, w1t);
    k_eff_b1<<<16, 256, 0, stream>>>(an_w1, an_b1, lvl_emb, effb1);
    k_rowlist<<<1, 1024, 0, stream>>>(labels, rowlist, gstart, gcnt, counts_f);
    k_gather<<<dim3(NCLS, 4), 256, 0, stream>>>(featb, DIM, rowlist, gstart, gcnt,
                                                counts_f, rawsum, 0);
    k_tasksum<<<4, 256, 0, stream>>>(rawsum, tc);
    k_gemv1<<<16, 512, 0, stream>>>(tc, sp_w1, hpre);
    k_head_fin<<<1, 512, 0, stream>>>(hpre, sp_b1, sp_w2, sp_b2, headf, headi, dout);

    // fused 4-level GEMM1: hh[16384][4096] = featb @ [W1_l]^T + eff_b1
    k_gemm256<<<dim3(64, 16), 512, 0, stream>>>(featb, w1t, effb1, hh, DIM, NFUSE, DIM / 64);
    k_ln_relu<<<dim3(N_SUP, NLV), 256, 0, stream>>>(hh, an_g, an_be);
    k_gather<<<dim3(NCLS, 16), 256, 0, stream>>>(hh, NFUSE, rowlist, gstart, gcnt,
                                                 counts_f, gsum, 1);
    // proto_pre[l] = gsum[:, l*1024:+1024] @ an_w2[l]
    k_fuse_gemm<<<dim3(16, 16, 4), 256, 0, stream>>>(gsum, NFUSE, 1024,
                                                     an_w2, 1024 * 1024,
                                                     proto_pre, NCLS * DIM, 1024);

    k_build_fi<<<(64 * 4160) / 256, 256, 0, stream>>>(proto_pre, an_b2, gcnt, headf, headi, fi);
    k_fuse_gemm<<<dim3(16, 65, 1), 256, 0, stream>>>(fi, 4160, 0, fu_w1, 0, h1pre, 0, 4100);
    k_bias_relu<<<NCLS * DIM / 256, 256, 0, stream>>>(h1pre, fu_b1, h1);
    k_fuse_gemm<<<dim3(16, 16, 1), 256, 0, stream>>>(h1, 1024, 0, fu_w2, 0, f2pre, 0, 1024);
    k_final<<<NCLS * DIM / 256, 256, 0, stream>>>(f2pre, fu_b2, headi, rawsum, counts_f, dout);
}

// Round 7
// 370.791 us; speedup vs baseline: 3.6968x; 1.1171x over previous
//
#include <hip/hip_runtime.h>
#include <hip/hip_bf16.h>
#include <stdint.h>

#define N_SUP 16384
#define DIM   1024
#define NLV   4
#define NCLS  64
#define NFUSE 4096          // 4 levels x 1024

typedef __bf16 bf16x8 __attribute__((ext_vector_type(8)));
typedef __bf16 bf16x4 __attribute__((ext_vector_type(4)));
typedef float  f32x4  __attribute__((ext_vector_type(4)));

#define GLOAD_LDS16(g, l) \
    __builtin_amdgcn_global_load_lds((const __attribute__((address_space(1))) void*)(g), \
                                     (__attribute__((address_space(3))) void*)(l), 16, 0, 0)

// ---------------- conversions ----------------
__global__ __launch_bounds__(256) void k_conv_feat(const float* __restrict__ f,
                                                   __bf16* __restrict__ o) {
    size_t i = ((size_t)blockIdx.x * 256 + threadIdx.x) * 4;
    float4 v = *(const float4*)(f + i);
    union { __bf16 b[4]; uint64_t u; } pk;
    pk.b[0] = (__bf16)v.x; pk.b[1] = (__bf16)v.y;
    pk.b[2] = (__bf16)v.z; pk.b[3] = (__bf16)v.w;
    *(uint64_t*)(o + i) = pk.u;
}

// transpose+convert an_w1[l][:1024][:] into N-major (N x K) bf16
__global__ __launch_bounds__(256) void k_wt(const float* __restrict__ an_w1,
                                            __bf16* __restrict__ w1t) {
    __shared__ float tile[64][65];
    int m = blockIdx.z;
    const float* src = an_w1 + (size_t)m * 1025 * 1024;
    __bf16* dst = w1t + (size_t)m * 1024 * 1024;
    int k0 = blockIdx.x * 64, n0 = blockIdx.y * 64;
    int j = threadIdx.x & 63, i0 = threadIdx.x >> 6;
    #pragma unroll
    for (int ii = 0; ii < 16; ++ii) {
        int i = i0 + ii * 4;
        tile[i][j] = src[(size_t)(k0 + i) * 1024 + n0 + j];
    }
    __syncthreads();
    #pragma unroll
    for (int ii = 0; ii < 16; ++ii) {
        int i = i0 + ii * 4;
        dst[(size_t)(n0 + i) * 1024 + k0 + j] = (__bf16)tile[j][i];
    }
}

// eff_b1[l][j] = an_b1[l][j] + lvl_emb[l] * an_w1[l][1024][j]
__global__ __launch_bounds__(256) void k_eff_b1(const float* __restrict__ an_w1,
                                                const float* __restrict__ an_b1,
                                                const float* __restrict__ lvl_emb,
                                                float* __restrict__ eff) {
    int i = blockIdx.x * 256 + threadIdx.x;      // 0..4095
    int l = i >> 10, j = i & 1023;
    eff[i] = an_b1[i] + lvl_emb[l] * an_w1[(size_t)l * 1025 * 1024 + (size_t)1024 * 1024 + j];
}

// build per-class row lists
__global__ __launch_bounds__(1024) void k_rowlist(const int* __restrict__ labels,
                                                  int* __restrict__ rowlist,
                                                  int* __restrict__ gstart,
                                                  int* __restrict__ gcnt,
                                                  float* __restrict__ counts_f) {
    __shared__ int cnt[NCLS];
    __shared__ int sstart[NCLS];
    __shared__ int cur[NCLS];
    int tid = threadIdx.x;
    if (tid < NCLS) cnt[tid] = 0;
    __syncthreads();
    for (int r = tid; r < N_SUP; r += 1024) atomicAdd(&cnt[labels[r]], 1);
    __syncthreads();
    if (tid == 0) {
        int run = 0;
        for (int c = 0; c < NCLS; ++c) { sstart[c] = run; run += cnt[c]; }
    }
    __syncthreads();
    if (tid < NCLS) {
        cur[tid] = sstart[tid];
        gstart[tid] = sstart[tid];
        gcnt[tid] = cnt[tid];
        counts_f[tid] = fmaxf((float)cnt[tid], 1.0f);
    }
    __syncthreads();
    for (int r = tid; r < N_SUP; r += 1024) {
        int pos = atomicAdd(&cur[labels[r]], 1);
        rowlist[pos] = r;
    }
}

// atomic-free segment sum (plain, for raw features); ld = row stride
__global__ __launch_bounds__(256) void k_gather(const __bf16* __restrict__ X, int ld,
                                                const int* __restrict__ rowlist,
                                                const int* __restrict__ gstart,
                                                const int* __restrict__ gcnt,
                                                const float* __restrict__ counts_f,
                                                float* __restrict__ outp, int div) {
    int c = blockIdx.x;
    int col = blockIdx.y * 256 + threadIdx.x;
    int st = gstart[c], n = gcnt[c];
    float acc = 0.f;
    int i = 0;
    for (; i + 8 <= n; i += 8) {
        int r[8];
        #pragma unroll
        for (int j = 0; j < 8; ++j) r[j] = rowlist[st + i + j];
        float v[8];
        #pragma unroll
        for (int j = 0; j < 8; ++j) v[j] = (float)X[(size_t)r[j] * ld + col];
        #pragma unroll
        for (int j = 0; j < 8; ++j) acc += v[j];
    }
    for (; i < n; ++i) acc += (float)X[(size_t)rowlist[st + i] * ld + col];
    float sc = div ? (1.0f / counts_f[c]) : 1.0f;
    outp[(size_t)c * ld + col] = acc * sc;
}

// tc[j] = (sum_c rawsum[c][j]) / N
__global__ __launch_bounds__(256) void k_tasksum(const float* __restrict__ rawsum,
                                                 float* __restrict__ tc) {
    int j = blockIdx.x * 256 + threadIdx.x;
    float t = 0.f;
    for (int c = 0; c < NCLS; ++c) t += rawsum[(size_t)c * DIM + j];
    tc[j] = t * (1.0f / N_SUP);
}

__global__ __launch_bounds__(512) void k_gemv1(const float* __restrict__ tc,
                                               const float* __restrict__ sp_w1,
                                               float* __restrict__ hpre) {
    __shared__ float tcs[64];
    int tid = threadIdx.x;
    int kb = blockIdx.x * 64;
    if (tid < 64) tcs[tid] = tc[kb + tid];
    __syncthreads();
    float acc = 0.f;
    #pragma unroll 8
    for (int k = 0; k < 64; ++k)
        acc += tcs[k] * sp_w1[(size_t)(kb + k) * 512 + tid];
    atomicAdd(&hpre[tid], acc);
}

__global__ __launch_bounds__(512) void k_head_fin(const float* __restrict__ hpre,
                                                  const float* __restrict__ sp_b1,
                                                  const float* __restrict__ sp_w2,
                                                  const float* __restrict__ sp_b2,
                                                  float* __restrict__ headf,
                                                  int* __restrict__ headi,
                                                  float* __restrict__ dout) {
    __shared__ float red[512];
    __shared__ float a4[4];
    int tid = threadIdx.x;
    float hv = hpre[tid] + sp_b1[tid];
    hv = hv > 0.f ? hv : 0.f;
    #pragma unroll
    for (int o = 0; o < 4; ++o) {
        red[tid] = hv * sp_w2[tid * 4 + o];
        __syncthreads();
        for (int st = 256; st > 0; st >>= 1) {
            if (tid < st) red[tid] += red[tid + st];
            __syncthreads();
        }
        if (tid == 0) a4[o] = 1.0f / (1.0f + expf(-(red[0] + sp_b2[o])));
        __syncthreads();
    }
    if (tid == 0) {
        int kk = 0;
        int lvl[4] = {-1, -1, -1, -1};
        for (int l = 0; l < 4; ++l)
            if (a4[l] > 0.1f) { lvl[kk] = l; kk++; }
        headi[0] = kk;
        for (int s = 0; s < 4; ++s) headi[1 + s] = lvl[s];
        for (int l = 0; l < 4; ++l) headf[l] = a4[l];
    }
    if (tid < 4) {
        dout[65536 + tid] = a4[tid];
        dout[65540 + tid] = a4[tid] > 0.1f ? a4[tid] : 0.f;
    }
}

// ==================== 256x256 pipelined bf16 MFMA GEMM ====================
// 8 waves (2M x 4N), BK=64, double-buffered 128KB LDS, XOR-swizzled LDS,
// one-ahead ds_read register pipeline (X/Y sets), 2 barriers + counted
// vmcnt(4) per K-tile, setprio(1) around MFMA clusters.
// PAIRING FIX vs R6: MFMA quadrant = DSREAD quadrant (both kk-halves of a
// quadrant accumulate into the SAME acc quadrant).
__global__ __launch_bounds__(512, 2) void k_gemm256(const __bf16* __restrict__ A,
                                                    const __bf16* __restrict__ Bt,
                                                    const float* __restrict__ bias,
                                                    __bf16* __restrict__ C,
                                                    int K, int Nn, int NT) {
    __shared__ __bf16 lds[65536];   // [buf][A|B][half][128][64]
    const int tid = threadIdx.x;
    const int w   = tid >> 6;       // wave 0..7
    const int l   = tid & 63;
    const int wr  = w >> 2;         // 0..1 (M)
    const int wc  = w & 3;          // 0..3 (N)
    const int am  = l & 15;
    const int kg  = l >> 4;         // 0..3
    const size_t bm = (size_t)blockIdx.x * 256;
    const size_t bn = (size_t)blockIdx.y * 256;

    const int srow = w * 8 + (l >> 3);
    const int scol = ((l & 7) ^ (l >> 3)) * 8;     // pre-swizzled source col
    const __bf16* gA[2][2]; const __bf16* gB[2][2];
    #pragma unroll
    for (int h = 0; h < 2; ++h)
        #pragma unroll
        for (int p = 0; p < 2; ++p) {
            gA[h][p] = A  + (bm + h * 128 + p * 64 + srow) * (size_t)K + scol;
            gB[h][p] = Bt + (bn + h * 128 + p * 64 + srow) * (size_t)K + scol;
        }

    f32x4 acc[8][4] = {};

    // prologue: stage tile 0 into buf0
    #pragma unroll
    for (int h = 0; h < 2; ++h)
        #pragma unroll
        for (int p = 0; p < 2; ++p) {
            GLOAD_LDS16(gA[h][p], lds + h * 8192 + p * 4096 + w * 512);
            GLOAD_LDS16(gB[h][p], lds + 16384 + h * 8192 + p * 4096 + w * 512);
        }

    const int swz = (am & 7) * 8;

#define DSREAD(q, kk, A0, A1, A2, A3, B0, B1) { \
    const int koff_ = (((kk) * 32 + kg * 8) ^ swz); \
    const __bf16* pa_ = lds + cb + wr * 8192 + koff_; \
    const __bf16* pb_ = lds + cb + 16384 + (wc >> 1) * 8192 + ((wc & 1) * 64) * 64 + koff_; \
    A0 = *(const bf16x8*)(pa_ + ((((q) >> 1) * 4 + 0) * 16 + am) * 64); \
    A1 = *(const bf16x8*)(pa_ + ((((q) >> 1) * 4 + 1) * 16 + am) * 64); \
    A2 = *(const bf16x8*)(pa_ + ((((q) >> 1) * 4 + 2) * 16 + am) * 64); \
    A3 = *(const bf16x8*)(pa_ + ((((q) >> 1) * 4 + 3) * 16 + am) * 64); \
    B0 = *(const bf16x8*)(pb_ + ((((q) & 1) * 2 + 0) * 16 + am) * 64); \
    B1 = *(const bf16x8*)(pb_ + ((((q) & 1) * 2 + 1) * 16 + am) * 64); }

#define MFMA8(q, A0, A1, A2, A3, B0, B1) \
    __builtin_amdgcn_s_setprio(1); \
    acc[((q) >> 1) * 4 + 0][((q) & 1) * 2 + 0] = __builtin_amdgcn_mfma_f32_16x16x32_bf16(A0, B0, acc[((q) >> 1) * 4 + 0][((q) & 1) * 2 + 0], 0, 0, 0); \
    acc[((q) >> 1) * 4 + 1][((q) & 1) * 2 + 0] = __builtin_amdgcn_mfma_f32_16x16x32_bf16(A1, B0, acc[((q) >> 1) * 4 + 1][((q) & 1) * 2 + 0], 0, 0, 0); \
    acc[((q) >> 1) * 4 + 2][((q) & 1) * 2 + 0] = __builtin_amdgcn_mfma_f32_16x16x32_bf16(A2, B0, acc[((q) >> 1) * 4 + 2][((q) & 1) * 2 + 0], 0, 0, 0); \
    acc[((q) >> 1) * 4 + 3][((q) & 1) * 2 + 0] = __builtin_amdgcn_mfma_f32_16x16x32_bf16(A3, B0, acc[((q) >> 1) * 4 + 3][((q) & 1) * 2 + 0], 0, 0, 0); \
    acc[((q) >> 1) * 4 + 0][((q) & 1) * 2 + 1] = __builtin_amdgcn_mfma_f32_16x16x32_bf16(A0, B1, acc[((q) >> 1) * 4 + 0][((q) & 1) * 2 + 1], 0, 0, 0); \
    acc[((q) >> 1) * 4 + 1][((q) & 1) * 2 + 1] = __builtin_amdgcn_mfma_f32_16x16x32_bf16(A1, B1, acc[((q) >> 1) * 4 + 1][((q) & 1) * 2 + 1], 0, 0, 0); \
    acc[((q) >> 1) * 4 + 2][((q) & 1) * 2 + 1] = __builtin_amdgcn_mfma_f32_16x16x32_bf16(A2, B1, acc[((q) >> 1) * 4 + 2][((q) & 1) * 2 + 1], 0, 0, 0); \
    acc[((q) >> 1) * 4 + 3][((q) & 1) * 2 + 1] = __builtin_amdgcn_mfma_f32_16x16x32_bf16(A3, B1, acc[((q) >> 1) * 4 + 3][((q) & 1) * 2 + 1], 0, 0, 0); \
    __builtin_amdgcn_s_setprio(0);

    for (int t = 0; t < NT; ++t) {
        const int cb = (t & 1) * 32768;
        const int nb = cb ^ 32768;
        const int tn = (t + 1) * 64;
        const bool more = (t + 1 < NT);
        if (more) {
            GLOAD_LDS16(gA[0][0] + tn, lds + nb + 0 * 4096 + w * 512);
            GLOAD_LDS16(gA[0][1] + tn, lds + nb + 1 * 4096 + w * 512);
            GLOAD_LDS16(gA[1][0] + tn, lds + nb + 8192 + 0 * 4096 + w * 512);
            GLOAD_LDS16(gA[1][1] + tn, lds + nb + 8192 + 1 * 4096 + w * 512);
            asm volatile("s_waitcnt vmcnt(4)" ::: "memory");   // tile t fully staged
        } else {
            asm volatile("s_waitcnt vmcnt(0)" ::: "memory");
        }
        __builtin_amdgcn_s_barrier();

        bf16x8 xa0, xa1, xa2, xa3, xb0, xb1;
        bf16x8 ya0, ya1, ya2, ya3, yb0, yb1;
        DSREAD(0, 0, xa0, xa1, xa2, xa3, xb0, xb1)
        if (more) {
            GLOAD_LDS16(gB[0][0] + tn, lds + nb + 16384 + 0 * 4096 + w * 512);
            GLOAD_LDS16(gB[0][1] + tn, lds + nb + 16384 + 1 * 4096 + w * 512);
        }
        DSREAD(0, 1, ya0, ya1, ya2, ya3, yb0, yb1)
        if (more) {
            GLOAD_LDS16(gB[1][0] + tn, lds + nb + 16384 + 8192 + 0 * 4096 + w * 512);
            GLOAD_LDS16(gB[1][1] + tn, lds + nb + 16384 + 8192 + 1 * 4096 + w * 512);
        }
        MFMA8(0, xa0, xa1, xa2, xa3, xb0, xb1)          // quad 0, kk=0
        DSREAD(1, 0, xa0, xa1, xa2, xa3, xb0, xb1)
        MFMA8(0, ya0, ya1, ya2, ya3, yb0, yb1)          // quad 0, kk=1
        DSREAD(1, 1, ya0, ya1, ya2, ya3, yb0, yb1)
        MFMA8(1, xa0, xa1, xa2, xa3, xb0, xb1)          // quad 1, kk=0
        DSREAD(2, 0, xa0, xa1, xa2, xa3, xb0, xb1)
        MFMA8(1, ya0, ya1, ya2, ya3, yb0, yb1)          // quad 1, kk=1
        DSREAD(2, 1, ya0, ya1, ya2, ya3, yb0, yb1)
        MFMA8(2, xa0, xa1, xa2, xa3, xb0, xb1)          // quad 2, kk=0
        DSREAD(3, 0, xa0, xa1, xa2, xa3, xb0, xb1)
        MFMA8(2, ya0, ya1, ya2, ya3, yb0, yb1)          // quad 2, kk=1
        DSREAD(3, 1, ya0, ya1, ya2, ya3, yb0, yb1)
        MFMA8(3, xa0, xa1, xa2, xa3, xb0, xb1)          // quad 3, kk=0
        MFMA8(3, ya0, ya1, ya2, ya3, yb0, yb1)          // quad 3, kk=1
        __builtin_amdgcn_s_barrier();                   // all reads of cb done
    }
#undef DSREAD
#undef MFMA8

    const int rbase = kg * 4;    // C/D: col=lane&15, row=(lane>>4)*4+reg
    #pragma unroll
    for (int m = 0; m < 8; ++m) {
        const size_t row = bm + wr * 128 + m * 16 + rbase;
        #pragma unroll
        for (int n = 0; n < 4; ++n) {
            const int col = (int)bn + wc * 64 + n * 16 + am;
            const float bv = bias[col];
            #pragma unroll
            for (int r = 0; r < 4; ++r)
                C[(row + r) * (size_t)Nn + col] = (__bf16)(acc[m][n][r] + bv);
        }
    }
}

// ============== fused LayerNorm+ReLU+segment-sum over hh ==============
// block = (class c, level lv, row-chunk z of 8). Accumulates raw sums into
// gsum (zero-initialized) via atomicAdd; count-division deferred to build_fi.
__global__ __launch_bounds__(256) void k_gather_ln(const __bf16* __restrict__ hh,
                                                   const float* __restrict__ an_g,
                                                   const float* __restrict__ an_be,
                                                   const int* __restrict__ rowlist,
                                                   const int* __restrict__ gstart,
                                                   const int* __restrict__ gcnt,
                                                   float* __restrict__ gsum) {
    int c = blockIdx.x, lv = blockIdx.y, z = blockIdx.z;
    int tid = threadIdx.x;
    int lane = tid & 63, wv = tid >> 6;
    int col = tid * 4;
    const float* gamma = an_g + lv * 1024;
    const float* beta  = an_be + lv * 1024;
    float g0 = gamma[col], g1 = gamma[col + 1], g2 = gamma[col + 2], g3 = gamma[col + 3];
    float b0 = beta[col],  b1 = beta[col + 1],  b2 = beta[col + 2],  b3 = beta[col + 3];
    int st = gstart[c], n = gcnt[c];
    int per = (n + 7) >> 3;
    int i0 = z * per;
    int i1 = i0 + per < n ? i0 + per : n;
    float a0 = 0.f, a1 = 0.f, a2 = 0.f, a3 = 0.f;
    __shared__ float sred[4], qred[4];
    for (int i = i0; i < i1; ++i) {
        int r = rowlist[st + i];
        bf16x4 v = *(const bf16x4*)(hh + (size_t)r * NFUSE + lv * 1024 + col);
        float x0 = (float)v[0], x1 = (float)v[1], x2 = (float)v[2], x3 = (float)v[3];
        float s = x0 + x1 + x2 + x3;
        float q = x0 * x0 + x1 * x1 + x2 * x2 + x3 * x3;
        s += __shfl_xor(s, 1);  q += __shfl_xor(q, 1);
        s += __shfl_xor(s, 2);  q += __shfl_xor(q, 2);
        s += __shfl_xor(s, 4);  q += __shfl_xor(q, 4);
        s += __shfl_xor(s, 8);  q += __shfl_xor(q, 8);
        s += __shfl_xor(s, 16); q += __shfl_xor(q, 16);
        s += __shfl_xor(s, 32); q += __shfl_xor(q, 32);
        if (lane == 0) { sred[wv] = s; qred[wv] = q; }
        __syncthreads();
        s = sred[0] + sred[1] + sred[2] + sred[3];
        q = qred[0] + qred[1] + qred[2] + qred[3];
        __syncthreads();
        float mu = s * (1.0f / DIM);
        float var = q * (1.0f / DIM) - mu * mu;
        float rstd = rsqrtf(var + 1e-5f);
        float y;
        y = (x0 - mu) * rstd * g0 + b0; a0 += y > 0.f ? y : 0.f;
        y = (x1 - mu) * rstd * g1 + b1; a1 += y > 0.f ? y : 0.f;
        y = (x2 - mu) * rstd * g2 + b2; a2 += y > 0.f ? y : 0.f;
        y = (x3 - mu) * rstd * g3 + b3; a3 += y > 0.f ? y : 0.f;
    }
    if (i0 < i1) {
        size_t o = (size_t)c * NFUSE + lv * 1024 + col;
        atomicAdd(&gsum[o],     a0);
        atomicAdd(&gsum[o + 1], a1);
        atomicAdd(&gsum[o + 2], a2);
        atomicAdd(&gsum[o + 3], a3);
    }
}

// fusion_input build: packed part = proto_pre[l][c][d]/cnt[c] + b2[l][d]
__global__ __launch_bounds__(256) void k_build_fi(const float* __restrict__ proto_pre,
                                                  const float* __restrict__ an_b2,
                                                  const int* __restrict__ gcnt,
                                                  const float* __restrict__ counts_f,
                                                  const float* __restrict__ headf,
                                                  const int* __restrict__ headi,
                                                  float* __restrict__ fi) {
    int idx = blockIdx.x * 256 + threadIdx.x;
    if (idx >= 64 * 4160) return;
    int c = idx / 4160, col = idx % 4160;
    int kk = headi[0];
    float v = 0.f;
    if (col < kk * 1024) {
        int s = col >> 10, d = col & 1023;
        int l = headi[1 + s];
        if (gcnt[c] > 0)
            v = proto_pre[((size_t)l * NCLS + c) * DIM + d] / counts_f[c]
                + an_b2[(size_t)l * DIM + d];
    } else if (col < kk * 1024 + kk) {
        int s = col - kk * 1024;
        v = headf[headi[1 + s]];
    }
    fi[idx] = v;
}

// f32 split-K GEMM (64 x 1024 out), z-strided variant, atomic accumulate
__global__ __launch_bounds__(256) void k_fuse_gemm(const float* __restrict__ Abase, int lda, int az,
                                                   const float* __restrict__ Wbase, int wz,
                                                   float* __restrict__ outbase, int oz,
                                                   int K) {
    const float* Afi = Abase + (size_t)blockIdx.z * az;
    const float* W   = Wbase + (size_t)blockIdx.z * wz;
    float* outp      = outbase + (size_t)blockIdx.z * oz;
    __shared__ float fi_lds[64][64];
    int tid = threadIdx.x;
    int tj = tid & 63, tg = tid >> 6;
    int jb = blockIdx.x;
    int k0 = blockIdx.y * 64;
    for (int i = tid; i < 64 * 64; i += 256) {
        int cc = i >> 6, kq = i & 63;
        fi_lds[cc][kq] = (k0 + kq < lda) ? Afi[(size_t)cc * lda + k0 + kq] : 0.f;
    }
    __syncthreads();
    float acc[16] = {};
    #pragma unroll 4
    for (int kq = 0; kq < 64; ++kq) {
        int kg = k0 + kq;
        float wv = (kg < K) ? W[(size_t)kg * 1024 + jb * 64 + tj] : 0.f;
        #pragma unroll
        for (int cc = 0; cc < 16; ++cc)
            acc[cc] += fi_lds[tg * 16 + cc][kq] * wv;
    }
    #pragma unroll
    for (int cc = 0; cc < 16; ++cc)
        atomicAdd(&outp[(size_t)(tg * 16 + cc) * 1024 + jb * 64 + tj], acc[cc]);
}

__global__ __launch_bounds__(256) void k_bias_relu(const float* __restrict__ pre,
                                                   const float* __restrict__ b,
                                                   float* __restrict__ outp) {
    int i = blockIdx.x * 256 + threadIdx.x;   // 65536
    int j = i & 1023;
    float v = pre[i] + b[j];
    outp[i] = v > 0.f ? v : 0.f;
}

__global__ __launch_bounds__(256) void k_final(const float* __restrict__ pre2,
                                               const float* __restrict__ fu_b2,
                                               const int* __restrict__ headi,
                                               const float* __restrict__ rawsum,
                                               const float* __restrict__ counts_f,
                                               float* __restrict__ dout) {
    int i = blockIdx.x * 256 + threadIdx.x;   // 65536
    int c = i >> 10, j = i & 1023;
    float v;
    if (headi[0] > 0) v = pre2[i] + fu_b2[j];
    else              v = rawsum[i] / counts_f[c];
    dout[i] = v;
}

extern "C" void kernel_launch(void* const* d_in, const int* in_sizes, int n_in,
                              void* d_out, int out_size, void* d_ws, size_t ws_size,
                              hipStream_t stream) {
    (void)in_sizes; (void)n_in; (void)out_size; (void)ws_size;
    const float* feat    = (const float*)d_in[0];
    const int*   labels  = (const int*)d_in[1];
    const float* sp_w1   = (const float*)d_in[2];
    const float* sp_b1   = (const float*)d_in[3];
    const float* sp_w2   = (const float*)d_in[4];
    const float* sp_b2   = (const float*)d_in[5];
    const float* lvl_emb = (const float*)d_in[6];
    const float* an_w1   = (const float*)d_in[7];
    const float* an_b1   = (const float*)d_in[8];
    const float* an_g    = (const float*)d_in[9];
    const float* an_be   = (const float*)d_in[10];
    const float* an_w2   = (const float*)d_in[11];
    const float* an_b2   = (const float*)d_in[12];
    const float* fu_w1   = (const float*)d_in[13];
    const float* fu_b1   = (const float*)d_in[14];
    const float* fu_w2   = (const float*)d_in[15];
    const float* fu_b2   = (const float*)d_in[16];
    float* dout = (float*)d_out;

    char* p = (char*)d_ws;
    auto alloc = [&](size_t b) { char* r = p; p += (b + 255) & ~(size_t)255; return r; };
    __bf16* featb = (__bf16*)alloc((size_t)N_SUP * DIM * 2);
    __bf16* w1t   = (__bf16*)alloc((size_t)NLV * DIM * DIM * 2);
    __bf16* hh    = (__bf16*)alloc((size_t)N_SUP * NFUSE * 2);
    float*  effb1 = (float*) alloc((size_t)NLV * DIM * 4);
    float*  fi    = (float*) alloc((size_t)64 * 4160 * 4);
    float*  h1    = (float*) alloc((size_t)NCLS * DIM * 4);
    float*  rawsum  = (float*)alloc((size_t)NCLS * DIM * 4);
    float*  tc      = (float*)alloc(DIM * 4);
    int*    rowlist = (int*)  alloc((size_t)N_SUP * 4);
    int*    gstart  = (int*)  alloc(NCLS * 4);
    int*    gcnt    = (int*)  alloc(NCLS * 4);
    float*  counts_f= (float*)alloc(NCLS * 4);
    float*  headf   = (float*)alloc(4 * 4);
    int*    headi   = (int*)  alloc(8 * 4);
    char* z0 = p;
    float*  gsum    = (float*)alloc((size_t)NCLS * NFUSE * 4);
    float*  proto_pre = (float*)alloc((size_t)NLV * NCLS * DIM * 4);
    float*  h1pre   = (float*)alloc((size_t)NCLS * DIM * 4);
    float*  f2pre   = (float*)alloc((size_t)NCLS * DIM * 4);
    float*  hpre    = (float*)alloc(512 * 4);
    size_t zbytes = (size_t)(p - z0);
    hipMemsetAsync(z0, 0, zbytes, stream);

    k_conv_feat<<<N_SUP * DIM / 4 / 256, 256, 0, stream>>>(feat, featb);
    k_wt<<<dim3(16, 16, 4), 256, 0, stream>>>(an_w1, w1t);
    k_eff_b1<<<16, 256, 0, stream>>>(an_w1, an_b1, lvl_emb, effb1);
    k_rowlist<<<1, 1024, 0, stream>>>(labels, rowlist, gstart, gcnt, counts_f);
    k_gather<<<dim3(NCLS, 4), 256, 0, stream>>>(featb, DIM, rowlist, gstart, gcnt,
                                                counts_f, rawsum, 0);
    k_tasksum<<<4, 256, 0, stream>>>(rawsum, tc);
    k_gemv1<<<16, 512, 0, stream>>>(tc, sp_w1, hpre);
    k_head_fin<<<1, 512, 0, stream>>>(hpre, sp_b1, sp_w2, sp_b2, headf, headi, dout);

    // fused 4-level GEMM1: hh[16384][4096] = featb @ [W1_l]^T + eff_b1
    k_gemm256<<<dim3(64, 16), 512, 0, stream>>>(featb, w1t, effb1, hh, DIM, NFUSE, DIM / 64);
    // fused LN+ReLU+segment-sum
    k_gather_ln<<<dim3(NCLS, NLV, 8), 256, 0, stream>>>(hh, an_g, an_be,
                                                        rowlist, gstart, gcnt, gsum);
    // proto_pre[l] = gsum[:, l*1024:+1024] @ an_w2[l]   (division by count in build_fi)
    k_fuse_gemm<<<dim3(16, 16, 4), 256, 0, stream>>>(gsum, NFUSE, 1024,
                                                     an_w2, 1024 * 1024,
                                                     proto_pre, NCLS * DIM, 1024);

    k_build_fi<<<(64 * 4160) / 256, 256, 0, stream>>>(proto_pre, an_b2, gcnt, counts_f,
                                                      headf, headi, fi);
    k_fuse_gemm<<<dim3(16, 65, 1), 256, 0, stream>>>(fi, 4160, 0, fu_w1, 0, h1pre, 0, 4100);
    k_bias_relu<<<NCLS * DIM / 256, 256, 0, stream>>>(h1pre, fu_b1, h1);
    k_fuse_gemm<<<dim3(16, 16, 1), 256, 0, stream>>>(h1, 1024, 0, fu_w2, 0, f2pre, 0, 1024);
    k_final<<<NCLS * DIM / 256, 256, 0, stream>>>(f2pre, fu_b2, headi, rawsum, counts_f, dout);
}

// Round 8
// 365.063 us; speedup vs baseline: 3.7549x; 1.0157x over previous
//
#include <hip/hip_runtime.h>
#include <hip/hip_bf16.h>
#include <stdint.h>

#define N_SUP 16384
#define DIM   1024
#define NLV   4
#define NCLS  64
#define NFUSE 4096          // 4 levels x 1024

typedef __bf16 bf16x8 __attribute__((ext_vector_type(8)));
typedef __bf16 bf16x4 __attribute__((ext_vector_type(4)));
typedef float  f32x4  __attribute__((ext_vector_type(4)));

#define GLOAD_LDS16(g, l) \
    __builtin_amdgcn_global_load_lds((const __attribute__((address_space(1))) void*)(g), \
                                     (__attribute__((address_space(3))) void*)(l), 16, 0, 0)

// ---------------- conversions ----------------
__global__ __launch_bounds__(256) void k_conv_feat(const float* __restrict__ f,
                                                   __bf16* __restrict__ o) {
    size_t i = ((size_t)blockIdx.x * 256 + threadIdx.x) * 4;
    float4 v = *(const float4*)(f + i);
    union { __bf16 b[4]; uint64_t u; } pk;
    pk.b[0] = (__bf16)v.x; pk.b[1] = (__bf16)v.y;
    pk.b[2] = (__bf16)v.z; pk.b[3] = (__bf16)v.w;
    *(uint64_t*)(o + i) = pk.u;
}

// transpose+convert an_w1[l][:1024][:] into N-major (N x K) bf16
__global__ __launch_bounds__(256) void k_wt(const float* __restrict__ an_w1,
                                            __bf16* __restrict__ w1t) {
    __shared__ float tile[64][65];
    int m = blockIdx.z;
    const float* src = an_w1 + (size_t)m * 1025 * 1024;
    __bf16* dst = w1t + (size_t)m * 1024 * 1024;
    int k0 = blockIdx.x * 64, n0 = blockIdx.y * 64;
    int j = threadIdx.x & 63, i0 = threadIdx.x >> 6;
    #pragma unroll
    for (int ii = 0; ii < 16; ++ii) {
        int i = i0 + ii * 4;
        tile[i][j] = src[(size_t)(k0 + i) * 1024 + n0 + j];
    }
    __syncthreads();
    #pragma unroll
    for (int ii = 0; ii < 16; ++ii) {
        int i = i0 + ii * 4;
        dst[(size_t)(n0 + i) * 1024 + k0 + j] = (__bf16)tile[j][i];
    }
}

// eff_b1[l][j] = an_b1[l][j] + lvl_emb[l] * an_w1[l][1024][j]
__global__ __launch_bounds__(256) void k_eff_b1(const float* __restrict__ an_w1,
                                                const float* __restrict__ an_b1,
                                                const float* __restrict__ lvl_emb,
                                                float* __restrict__ eff) {
    int i = blockIdx.x * 256 + threadIdx.x;      // 0..4095
    int l = i >> 10, j = i & 1023;
    eff[i] = an_b1[i] + lvl_emb[l] * an_w1[(size_t)l * 1025 * 1024 + (size_t)1024 * 1024 + j];
}

// build per-class row lists
__global__ __launch_bounds__(1024) void k_rowlist(const int* __restrict__ labels,
                                                  int* __restrict__ rowlist,
                                                  int* __restrict__ gstart,
                                                  int* __restrict__ gcnt,
                                                  float* __restrict__ counts_f) {
    __shared__ int cnt[NCLS];
    __shared__ int sstart[NCLS];
    __shared__ int cur[NCLS];
    int tid = threadIdx.x;
    if (tid < NCLS) cnt[tid] = 0;
    __syncthreads();
    for (int r = tid; r < N_SUP; r += 1024) atomicAdd(&cnt[labels[r]], 1);
    __syncthreads();
    if (tid == 0) {
        int run = 0;
        for (int c = 0; c < NCLS; ++c) { sstart[c] = run; run += cnt[c]; }
    }
    __syncthreads();
    if (tid < NCLS) {
        cur[tid] = sstart[tid];
        gstart[tid] = sstart[tid];
        gcnt[tid] = cnt[tid];
        counts_f[tid] = fmaxf((float)cnt[tid], 1.0f);
    }
    __syncthreads();
    for (int r = tid; r < N_SUP; r += 1024) {
        int pos = atomicAdd(&cur[labels[r]], 1);
        rowlist[pos] = r;
    }
}

// atomic-free segment sum (raw features); also accumulates column totals into
// tcsum (for task_context) when div==0. ld = row stride.
__global__ __launch_bounds__(256) void k_gather(const __bf16* __restrict__ X, int ld,
                                                const int* __restrict__ rowlist,
                                                const int* __restrict__ gstart,
                                                const int* __restrict__ gcnt,
                                                const float* __restrict__ counts_f,
                                                float* __restrict__ outp,
                                                float* __restrict__ tcsum, int div) {
    int c = blockIdx.x;
    int col = blockIdx.y * 256 + threadIdx.x;
    int st = gstart[c], n = gcnt[c];
    float acc = 0.f;
    int i = 0;
    for (; i + 8 <= n; i += 8) {
        int r[8];
        #pragma unroll
        for (int j = 0; j < 8; ++j) r[j] = rowlist[st + i + j];
        float v[8];
        #pragma unroll
        for (int j = 0; j < 8; ++j) v[j] = (float)X[(size_t)r[j] * ld + col];
        #pragma unroll
        for (int j = 0; j < 8; ++j) acc += v[j];
    }
    for (; i < n; ++i) acc += (float)X[(size_t)rowlist[st + i] * ld + col];
    float sc = div ? (1.0f / counts_f[c]) : 1.0f;
    outp[(size_t)c * ld + col] = acc * sc;
    if (!div) atomicAdd(&tcsum[col], acc);
}

__global__ __launch_bounds__(512) void k_gemv1(const float* __restrict__ tc,
                                               const float* __restrict__ sp_w1,
                                               float* __restrict__ hpre) {
    __shared__ float tcs[64];
    int tid = threadIdx.x;
    int kb = blockIdx.x * 64;
    if (tid < 64) tcs[tid] = tc[kb + tid] * (1.0f / N_SUP);
    __syncthreads();
    float acc = 0.f;
    #pragma unroll 8
    for (int k = 0; k < 64; ++k)
        acc += tcs[k] * sp_w1[(size_t)(kb + k) * 512 + tid];
    atomicAdd(&hpre[tid], acc);
}

__global__ __launch_bounds__(512) void k_head_fin(const float* __restrict__ hpre,
                                                  const float* __restrict__ sp_b1,
                                                  const float* __restrict__ sp_w2,
                                                  const float* __restrict__ sp_b2,
                                                  float* __restrict__ headf,
                                                  int* __restrict__ headi,
                                                  float* __restrict__ dout) {
    __shared__ float red[512];
    __shared__ float a4[4];
    int tid = threadIdx.x;
    float hv = hpre[tid] + sp_b1[tid];
    hv = hv > 0.f ? hv : 0.f;
    #pragma unroll
    for (int o = 0; o < 4; ++o) {
        red[tid] = hv * sp_w2[tid * 4 + o];
        __syncthreads();
        for (int st = 256; st > 0; st >>= 1) {
            if (tid < st) red[tid] += red[tid + st];
            __syncthreads();
        }
        if (tid == 0) a4[o] = 1.0f / (1.0f + expf(-(red[0] + sp_b2[o])));
        __syncthreads();
    }
    if (tid == 0) {
        int kk = 0;
        int lvl[4] = {-1, -1, -1, -1};
        for (int l = 0; l < 4; ++l)
            if (a4[l] > 0.1f) { lvl[kk] = l; kk++; }
        headi[0] = kk;
        for (int s = 0; s < 4; ++s) headi[1 + s] = lvl[s];
        for (int l = 0; l < 4; ++l) headf[l] = a4[l];
    }
    if (tid < 4) {
        dout[65536 + tid] = a4[tid];
        dout[65540 + tid] = a4[tid] > 0.1f ? a4[tid] : 0.f;
    }
}

// ==================== 256x256 4-phase bf16 MFMA GEMM (m201 schedule) ====
// 8 waves (2M x 4N), BK=64, double-buffered 128KB LDS, XOR-swizzled LDS.
// Per phase: {2 stage-loads of tile t+1, ds_read only NEW fragments,
// setprio(1), 16 MFMA, setprio(0), barrier}. Fragments cached across the
// quadrant pairs (A shared by q0/q1, B-low by q0/q2, B-high by q1/q3):
// 24 ds_read_b128/tile/wave instead of 48. Tile boundary: vmcnt(2)+barrier.
__global__ __launch_bounds__(512, 2) void k_gemm256(const __bf16* __restrict__ A,
                                                    const __bf16* __restrict__ Bt,
                                                    const float* __restrict__ bias,
                                                    __bf16* __restrict__ C,
                                                    int K, int Nn, int NT) {
    __shared__ __bf16 lds[65536];   // [buf][A|B][half][128][64]
    const int tid = threadIdx.x;
    const int w   = tid >> 6;       // wave 0..7
    const int l   = tid & 63;
    const int wr  = w >> 2;         // 0..1 (M)
    const int wc  = w & 3;          // 0..3 (N)
    const int am  = l & 15;
    const int kg  = l >> 4;         // 0..3
    const size_t bm = (size_t)blockIdx.x * 256;
    const size_t bn = (size_t)blockIdx.y * 256;

    const int srow = w * 8 + (l >> 3);
    const int scol = ((l & 7) ^ (l >> 3)) * 8;     // pre-swizzled source col
    const __bf16* gA[2][2]; const __bf16* gB[2][2];
    #pragma unroll
    for (int h = 0; h < 2; ++h)
        #pragma unroll
        for (int p = 0; p < 2; ++p) {
            gA[h][p] = A  + (bm + h * 128 + p * 64 + srow) * (size_t)K + scol;
            gB[h][p] = Bt + (bn + h * 128 + p * 64 + srow) * (size_t)K + scol;
        }

    f32x4 acc[8][4] = {};

    // prologue: stage tile 0 into buf0 (8 loads)
    #pragma unroll
    for (int h = 0; h < 2; ++h)
        #pragma unroll
        for (int p = 0; p < 2; ++p) {
            GLOAD_LDS16(gA[h][p], lds + h * 8192 + p * 4096 + w * 512);
            GLOAD_LDS16(gB[h][p], lds + 16384 + h * 8192 + p * 4096 + w * 512);
        }

    const int swz = (am & 7) * 8;

    for (int t = 0; t < NT; ++t) {
        const int cb = (t & 1) * 32768;
        const int nb = cb ^ 32768;
        const int tn = (t + 1) * 64;
        const bool more = (t + 1 < NT);
        bf16x8 ax[4][2], ay[4][2], bx[2][2], by[2][2];
        const __bf16* pa = lds + cb + wr * 8192;
        const __bf16* pb = lds + cb + 16384 + (wc >> 1) * 8192 + ((wc & 1) * 64) * 64;

        // ---------- phase 0: A-low(8) + B-low(4) reads; MFMA quad 0 ----------
        if (more) {
            GLOAD_LDS16(gA[0][0] + tn, lds + nb + 0 * 4096 + w * 512);
            GLOAD_LDS16(gA[0][1] + tn, lds + nb + 1 * 4096 + w * 512);
            asm volatile("s_waitcnt vmcnt(2)" ::: "memory");   // tile t resident, 2 in flight
        } else {
            asm volatile("s_waitcnt vmcnt(0)" ::: "memory");
        }
        __builtin_amdgcn_s_barrier();
        #pragma unroll
        for (int i = 0; i < 4; ++i)
            #pragma unroll
            for (int kk = 0; kk < 2; ++kk)
                ax[i][kk] = *(const bf16x8*)(pa + (i * 16 + am) * 64 + ((kk * 32 + kg * 8) ^ swz));
        #pragma unroll
        for (int j = 0; j < 2; ++j)
            #pragma unroll
            for (int kk = 0; kk < 2; ++kk)
                bx[j][kk] = *(const bf16x8*)(pb + (j * 16 + am) * 64 + ((kk * 32 + kg * 8) ^ swz));
        __builtin_amdgcn_s_setprio(1);
        #pragma unroll
        for (int i = 0; i < 4; ++i)
            #pragma unroll
            for (int j = 0; j < 2; ++j)
                #pragma unroll
                for (int kk = 0; kk < 2; ++kk)
                    acc[i][j] = __builtin_amdgcn_mfma_f32_16x16x32_bf16(ax[i][kk], bx[j][kk], acc[i][j], 0, 0, 0);
        __builtin_amdgcn_s_setprio(0);
        __builtin_amdgcn_s_barrier();

        // ---------- phase 1: B-high(4) reads; MFMA quad 1 (ax x by) ----------
        if (more) {
            GLOAD_LDS16(gA[1][0] + tn, lds + nb + 8192 + 0 * 4096 + w * 512);
            GLOAD_LDS16(gA[1][1] + tn, lds + nb + 8192 + 1 * 4096 + w * 512);
        }
        #pragma unroll
        for (int j = 0; j < 2; ++j)
            #pragma unroll
            for (int kk = 0; kk < 2; ++kk)
                by[j][kk] = *(const bf16x8*)(pb + ((2 + j) * 16 + am) * 64 + ((kk * 32 + kg * 8) ^ swz));
        __builtin_amdgcn_s_setprio(1);
        #pragma unroll
        for (int i = 0; i < 4; ++i)
            #pragma unroll
            for (int j = 0; j < 2; ++j)
                #pragma unroll
                for (int kk = 0; kk < 2; ++kk)
                    acc[i][2 + j] = __builtin_amdgcn_mfma_f32_16x16x32_bf16(ax[i][kk], by[j][kk], acc[i][2 + j], 0, 0, 0);
        __builtin_amdgcn_s_setprio(0);
        __builtin_amdgcn_s_barrier();

        // ---------- phase 2: A-high(8) reads; MFMA quad 2 (ay x bx) ----------
        if (more) {
            GLOAD_LDS16(gB[0][0] + tn, lds + nb + 16384 + 0 * 4096 + w * 512);
            GLOAD_LDS16(gB[0][1] + tn, lds + nb + 16384 + 1 * 4096 + w * 512);
        }
        #pragma unroll
        for (int i = 0; i < 4; ++i)
            #pragma unroll
            for (int kk = 0; kk < 2; ++kk)
                ay[i][kk] = *(const bf16x8*)(pa + ((4 + i) * 16 + am) * 64 + ((kk * 32 + kg * 8) ^ swz));
        __builtin_amdgcn_s_setprio(1);
        #pragma unroll
        for (int i = 0; i < 4; ++i)
            #pragma unroll
            for (int j = 0; j < 2; ++j)
                #pragma unroll
                for (int kk = 0; kk < 2; ++kk)
                    acc[4 + i][j] = __builtin_amdgcn_mfma_f32_16x16x32_bf16(ay[i][kk], bx[j][kk], acc[4 + i][j], 0, 0, 0);
        __builtin_amdgcn_s_setprio(0);
        __builtin_amdgcn_s_barrier();

        // ---------- phase 3: no reads; MFMA quad 3 (ay x by) ----------
        if (more) {
            GLOAD_LDS16(gB[1][0] + tn, lds + nb + 16384 + 8192 + 0 * 4096 + w * 512);
            GLOAD_LDS16(gB[1][1] + tn, lds + nb + 16384 + 8192 + 1 * 4096 + w * 512);
        }
        __builtin_amdgcn_s_setprio(1);
        #pragma unroll
        for (int i = 0; i < 4; ++i)
            #pragma unroll
            for (int j = 0; j < 2; ++j)
                #pragma unroll
                for (int kk = 0; kk < 2; ++kk)
                    acc[4 + i][2 + j] = __builtin_amdgcn_mfma_f32_16x16x32_bf16(ay[i][kk], by[j][kk], acc[4 + i][2 + j], 0, 0, 0);
        __builtin_amdgcn_s_setprio(0);
        __builtin_amdgcn_s_barrier();
    }

    const int rbase = kg * 4;    // C/D: col=lane&15, row=(lane>>4)*4+reg
    #pragma unroll
    for (int m = 0; m < 8; ++m) {
        const size_t row = bm + wr * 128 + m * 16 + rbase;
        #pragma unroll
        for (int n = 0; n < 4; ++n) {
            const int col = (int)bn + wc * 64 + n * 16 + am;
            const float bv = bias[col];
            #pragma unroll
            for (int r = 0; r < 4; ++r)
                C[(row + r) * (size_t)Nn + col] = (__bf16)(acc[m][n][r] + bv);
        }
    }
}

// ============== fused LayerNorm+ReLU+segment-sum over hh ==============
__global__ __launch_bounds__(256) void k_gather_ln(const __bf16* __restrict__ hh,
                                                   const float* __restrict__ an_g,
                                                   const float* __restrict__ an_be,
                                                   const int* __restrict__ rowlist,
                                                   const int* __restrict__ gstart,
                                                   const int* __restrict__ gcnt,
                                                   float* __restrict__ gsum) {
    int c = blockIdx.x, lv = blockIdx.y, z = blockIdx.z;
    int tid = threadIdx.x;
    int lane = tid & 63, wv = tid >> 6;
    int col = tid * 4;
    const float* gamma = an_g + lv * 1024;
    const float* beta  = an_be + lv * 1024;
    float g0 = gamma[col], g1 = gamma[col + 1], g2 = gamma[col + 2], g3 = gamma[col + 3];
    float b0 = beta[col],  b1 = beta[col + 1],  b2 = beta[col + 2],  b3 = beta[col + 3];
    int st = gstart[c], n = gcnt[c];
    int per = (n + 7) >> 3;
    int i0 = z * per;
    int i1 = i0 + per < n ? i0 + per : n;
    float a0 = 0.f, a1 = 0.f, a2 = 0.f, a3 = 0.f;
    __shared__ float sred[4], qred[4];
    for (int i = i0; i < i1; ++i) {
        int r = rowlist[st + i];
        bf16x4 v = *(const bf16x4*)(hh + (size_t)r * NFUSE + lv * 1024 + col);
        float x0 = (float)v[0], x1 = (float)v[1], x2 = (float)v[2], x3 = (float)v[3];
        float s = x0 + x1 + x2 + x3;
        float q = x0 * x0 + x1 * x1 + x2 * x2 + x3 * x3;
        s += __shfl_xor(s, 1);  q += __shfl_xor(q, 1);
        s += __shfl_xor(s, 2);  q += __shfl_xor(q, 2);
        s += __shfl_xor(s, 4);  q += __shfl_xor(q, 4);
        s += __shfl_xor(s, 8);  q += __shfl_xor(q, 8);
        s += __shfl_xor(s, 16); q += __shfl_xor(q, 16);
        s += __shfl_xor(s, 32); q += __shfl_xor(q, 32);
        if (lane == 0) { sred[wv] = s; qred[wv] = q; }
        __syncthreads();
        s = sred[0] + sred[1] + sred[2] + sred[3];
        q = qred[0] + qred[1] + qred[2] + qred[3];
        __syncthreads();
        float mu = s * (1.0f / DIM);
        float var = q * (1.0f / DIM) - mu * mu;
        float rstd = rsqrtf(var + 1e-5f);
        float y;
        y = (x0 - mu) * rstd * g0 + b0; a0 += y > 0.f ? y : 0.f;
        y = (x1 - mu) * rstd * g1 + b1; a1 += y > 0.f ? y : 0.f;
        y = (x2 - mu) * rstd * g2 + b2; a2 += y > 0.f ? y : 0.f;
        y = (x3 - mu) * rstd * g3 + b3; a3 += y > 0.f ? y : 0.f;
    }
    if (i0 < i1) {
        size_t o = (size_t)c * NFUSE + lv * 1024 + col;
        atomicAdd(&gsum[o],     a0);
        atomicAdd(&gsum[o + 1], a1);
        atomicAdd(&gsum[o + 2], a2);
        atomicAdd(&gsum[o + 3], a3);
    }
}

// fusion_input build: packed part = proto_pre[l][c][d]/cnt[c] + b2[l][d]
__global__ __launch_bounds__(256) void k_build_fi(const float* __restrict__ proto_pre,
                                                  const float* __restrict__ an_b2,
                                                  const int* __restrict__ gcnt,
                                                  const float* __restrict__ counts_f,
                                                  const float* __restrict__ headf,
                                                  const int* __restrict__ headi,
                                                  float* __restrict__ fi) {
    int idx = blockIdx.x * 256 + threadIdx.x;
    if (idx >= 64 * 4160) return;
    int c = idx / 4160, col = idx % 4160;
    int kk = headi[0];
    float v = 0.f;
    if (col < kk * 1024) {
        int s = col >> 10, d = col & 1023;
        int l = headi[1 + s];
        if (gcnt[c] > 0)
            v = proto_pre[((size_t)l * NCLS + c) * DIM + d] / counts_f[c]
                + an_b2[(size_t)l * DIM + d];
    } else if (col < kk * 1024 + kk) {
        int s = col - kk * 1024;
        v = headf[headi[1 + s]];
    }
    fi[idx] = v;
}

// f32 split-K GEMM (64 x 1024 out), z-strided variant, atomic accumulate
__global__ __launch_bounds__(256) void k_fuse_gemm(const float* __restrict__ Abase, int lda, int az,
                                                   const float* __restrict__ Wbase, int wz,
                                                   float* __restrict__ outbase, int oz,
                                                   int K) {
    const float* Afi = Abase + (size_t)blockIdx.z * az;
    const float* W   = Wbase + (size_t)blockIdx.z * wz;
    float* outp      = outbase + (size_t)blockIdx.z * oz;
    __shared__ float fi_lds[64][64];
    int tid = threadIdx.x;
    int tj = tid & 63, tg = tid >> 6;
    int jb = blockIdx.x;
    int k0 = blockIdx.y * 64;
    for (int i = tid; i < 64 * 64; i += 256) {
        int cc = i >> 6, kq = i & 63;
        fi_lds[cc][kq] = (k0 + kq < lda) ? Afi[(size_t)cc * lda + k0 + kq] : 0.f;
    }
    __syncthreads();
    float acc[16] = {};
    #pragma unroll 4
    for (int kq = 0; kq < 64; ++kq) {
        int kg = k0 + kq;
        float wv = (kg < K) ? W[(size_t)kg * 1024 + jb * 64 + tj] : 0.f;
        #pragma unroll
        for (int cc = 0; cc < 16; ++cc)
            acc[cc] += fi_lds[tg * 16 + cc][kq] * wv;
    }
    #pragma unroll
    for (int cc = 0; cc < 16; ++cc)
        atomicAdd(&outp[(size_t)(tg * 16 + cc) * 1024 + jb * 64 + tj], acc[cc]);
}

__global__ __launch_bounds__(256) void k_bias_relu(const float* __restrict__ pre,
                                                   const float* __restrict__ b,
                                                   float* __restrict__ outp) {
    int i = blockIdx.x * 256 + threadIdx.x;   // 65536
    int j = i & 1023;
    float v = pre[i] + b[j];
    outp[i] = v > 0.f ? v : 0.f;
}

__global__ __launch_bounds__(256) void k_final(const float* __restrict__ pre2,
                                               const float* __restrict__ fu_b2,
                                               const int* __restrict__ headi,
                                               const float* __restrict__ rawsum,
                                               const float* __restrict__ counts_f,
                                               float* __restrict__ dout) {
    int i = blockIdx.x * 256 + threadIdx.x;   // 65536
    int c = i >> 10, j = i & 1023;
    float v;
    if (headi[0] > 0) v = pre2[i] + fu_b2[j];
    else              v = rawsum[i] / counts_f[c];
    dout[i] = v;
}

extern "C" void kernel_launch(void* const* d_in, const int* in_sizes, int n_in,
                              void* d_out, int out_size, void* d_ws, size_t ws_size,
                              hipStream_t stream) {
    (void)in_sizes; (void)n_in; (void)out_size; (void)ws_size;
    const float* feat    = (const float*)d_in[0];
    const int*   labels  = (const int*)d_in[1];
    const float* sp_w1   = (const float*)d_in[2];
    const float* sp_b1   = (const float*)d_in[3];
    const float* sp_w2   = (const float*)d_in[4];
    const float* sp_b2   = (const float*)d_in[5];
    const float* lvl_emb = (const float*)d_in[6];
    const float* an_w1   = (const float*)d_in[7];
    const float* an_b1   = (const float*)d_in[8];
    const float* an_g    = (const float*)d_in[9];
    const float* an_be   = (const float*)d_in[10];
    const float* an_w2   = (const float*)d_in[11];
    const float* an_b2   = (const float*)d_in[12];
    const float* fu_w1   = (const float*)d_in[13];
    const float* fu_b1   = (const float*)d_in[14];
    const float* fu_w2   = (const float*)d_in[15];
    const float* fu_b2   = (const float*)d_in[16];
    float* dout = (float*)d_out;

    char* p = (char*)d_ws;
    auto alloc = [&](size_t b) { char* r = p; p += (b + 255) & ~(size_t)255; return r; };
    __bf16* featb = (__bf16*)alloc((size_t)N_SUP * DIM * 2);
    __bf16* w1t   = (__bf16*)alloc((size_t)NLV * DIM * DIM * 2);
    __bf16* hh    = (__bf16*)alloc((size_t)N_SUP * NFUSE * 2);
    float*  effb1 = (float*) alloc((size_t)NLV * DIM * 4);
    float*  fi    = (float*) alloc((size_t)64 * 4160 * 4);
    float*  h1    = (float*) alloc((size_t)NCLS * DIM * 4);
    float*  rawsum  = (float*)alloc((size_t)NCLS * DIM * 4);
    int*    rowlist = (int*)  alloc((size_t)N_SUP * 4);
    int*    gstart  = (int*)  alloc(NCLS * 4);
    int*    gcnt    = (int*)  alloc(NCLS * 4);
    float*  counts_f= (float*)alloc(NCLS * 4);
    float*  headf   = (float*)alloc(4 * 4);
    int*    headi   = (int*)  alloc(8 * 4);
    char* z0 = p;
    float*  tc      = (float*)alloc(DIM * 4);
    float*  gsum    = (float*)alloc((size_t)NCLS * NFUSE * 4);
    float*  proto_pre = (float*)alloc((size_t)NLV * NCLS * DIM * 4);
    float*  h1pre   = (float*)alloc((size_t)NCLS * DIM * 4);
    float*  f2pre   = (float*)alloc((size_t)NCLS * DIM * 4);
    float*  hpre    = (float*)alloc(512 * 4);
    size_t zbytes = (size_t)(p - z0);
    hipMemsetAsync(z0, 0, zbytes, stream);

    k_conv_feat<<<N_SUP * DIM / 4 / 256, 256, 0, stream>>>(feat, featb);
    k_wt<<<dim3(16, 16, 4), 256, 0, stream>>>(an_w1, w1t);
    k_eff_b1<<<16, 256, 0, stream>>>(an_w1, an_b1, lvl_emb, effb1);
    k_rowlist<<<1, 1024, 0, stream>>>(labels, rowlist, gstart, gcnt, counts_f);
    k_gather<<<dim3(NCLS, 4), 256, 0, stream>>>(featb, DIM, rowlist, gstart, gcnt,
                                                counts_f, rawsum, tc, 0);
    k_gemv1<<<16, 512, 0, stream>>>(tc, sp_w1, hpre);
    k_head_fin<<<1, 512, 0, stream>>>(hpre, sp_b1, sp_w2, sp_b2, headf, headi, dout);

    // fused 4-level GEMM1: hh[16384][4096] = featb @ [W1_l]^T + eff_b1
    k_gemm256<<<dim3(64, 16), 512, 0, stream>>>(featb, w1t, effb1, hh, DIM, NFUSE, DIM / 64);
    // fused LN+ReLU+segment-sum
    k_gather_ln<<<dim3(NCLS, NLV, 8), 256, 0, stream>>>(hh, an_g, an_be,
                                                        rowlist, gstart, gcnt, gsum);
    // proto_pre[l] = gsum[:, l*1024:+1024] @ an_w2[l]   (division by count in build_fi)
    k_fuse_gemm<<<dim3(16, 16, 4), 256, 0, stream>>>(gsum, NFUSE, 1024,
                                                     an_w2, 1024 * 1024,
                                                     proto_pre, NCLS * DIM, 1024);

    k_build_fi<<<(64 * 4160) / 256, 256, 0, stream>>>(proto_pre, an_b2, gcnt, counts_f,
                                                      headf, headi, fi);
    k_fuse_gemm<<<dim3(16, 65, 1), 256, 0, stream>>>(fi, 4160, 0, fu_w1, 0, h1pre, 0, 4100);
    k_bias_relu<<<NCLS * DIM / 256, 256, 0, stream>>>(h1pre, fu_b1, h1);
    k_fuse_gemm<<<dim3(16, 16, 1), 256, 0, stream>>>(h1, 1024, 0, fu_w2, 0, f2pre, 0, 1024);
    k_final<<<NCLS * DIM / 256, 256, 0, stream>>>(f2pre, fu_b2, headi, rawsum, counts_f, dout);
}

// Round 9
// 328.832 us; speedup vs baseline: 4.1686x; 1.1102x over previous
//
#include <hip/hip_runtime.h>
#include <hip/hip_bf16.h>
#include <stdint.h>

#define N_SUP 16384
#define DIM   1024
#define NLV   4
#define NCLS  64
#define NFUSE 4096          // 4 levels x 1024

typedef __bf16 bf16x8 __attribute__((ext_vector_type(8)));
typedef __bf16 bf16x4 __attribute__((ext_vector_type(4)));
typedef float  f32x4  __attribute__((ext_vector_type(4)));

#define GLOAD_LDS16(g, l) \
    __builtin_amdgcn_global_load_lds((const __attribute__((address_space(1))) void*)(g), \
                                     (__attribute__((address_space(3))) void*)(l), 16, 0, 0)

// build per-class ranges + inverse permutation (sorted-by-class row order)
__global__ __launch_bounds__(1024) void k_rowlist(const int* __restrict__ labels,
                                                  int* __restrict__ inv,
                                                  int* __restrict__ gstart,
                                                  int* __restrict__ gcnt,
                                                  float* __restrict__ counts_f) {
    __shared__ int cnt[NCLS];
    __shared__ int sstart[NCLS];
    __shared__ int cur[NCLS];
    int tid = threadIdx.x;
    if (tid < NCLS) cnt[tid] = 0;
    __syncthreads();
    for (int r = tid; r < N_SUP; r += 1024) atomicAdd(&cnt[labels[r]], 1);
    __syncthreads();
    if (tid == 0) {
        int run = 0;
        for (int c = 0; c < NCLS; ++c) { sstart[c] = run; run += cnt[c]; }
    }
    __syncthreads();
    if (tid < NCLS) {
        cur[tid] = sstart[tid];
        gstart[tid] = sstart[tid];
        gcnt[tid] = cnt[tid];
        counts_f[tid] = fmaxf((float)cnt[tid], 1.0f);
    }
    __syncthreads();
    for (int r = tid; r < N_SUP; r += 1024) {
        int pos = atomicAdd(&cur[labels[r]], 1);
        inv[r] = pos;
    }
}

// convert + permute: featb[inv[r]] = bf16(feat[r]); block = one row
__global__ __launch_bounds__(256) void k_conv_feat(const float* __restrict__ f,
                                                   const int* __restrict__ inv,
                                                   __bf16* __restrict__ o) {
    int r = blockIdx.x;
    int tid = threadIdx.x;
    int dr = inv[r];
    float4 v = *(const float4*)(f + (size_t)r * DIM + tid * 4);
    union { __bf16 b[4]; uint64_t u; } pk;
    pk.b[0] = (__bf16)v.x; pk.b[1] = (__bf16)v.y;
    pk.b[2] = (__bf16)v.z; pk.b[3] = (__bf16)v.w;
    *(uint64_t*)(o + (size_t)dr * DIM + tid * 4) = pk.u;
}

// transpose+convert an_w1[l][:1024][:] into N-major (N x K) bf16
__global__ __launch_bounds__(256) void k_wt(const float* __restrict__ an_w1,
                                            __bf16* __restrict__ w1t) {
    __shared__ float tile[64][65];
    int m = blockIdx.z;
    const float* src = an_w1 + (size_t)m * 1025 * 1024;
    __bf16* dst = w1t + (size_t)m * 1024 * 1024;
    int k0 = blockIdx.x * 64, n0 = blockIdx.y * 64;
    int j = threadIdx.x & 63, i0 = threadIdx.x >> 6;
    #pragma unroll
    for (int ii = 0; ii < 16; ++ii) {
        int i = i0 + ii * 4;
        tile[i][j] = src[(size_t)(k0 + i) * 1024 + n0 + j];
    }
    __syncthreads();
    #pragma unroll
    for (int ii = 0; ii < 16; ++ii) {
        int i = i0 + ii * 4;
        dst[(size_t)(n0 + i) * 1024 + k0 + j] = (__bf16)tile[j][i];
    }
}

// eff_b1[l][j] = an_b1[l][j] + lvl_emb[l] * an_w1[l][1024][j]
__global__ __launch_bounds__(256) void k_eff_b1(const float* __restrict__ an_w1,
                                                const float* __restrict__ an_b1,
                                                const float* __restrict__ lvl_emb,
                                                float* __restrict__ eff) {
    int i = blockIdx.x * 256 + threadIdx.x;      // 0..4095
    int l = i >> 10, j = i & 1023;
    eff[i] = an_b1[i] + lvl_emb[l] * an_w1[(size_t)l * 1025 * 1024 + (size_t)1024 * 1024 + j];
}

// contiguous segment sum over sorted featb; also column totals for task_context
__global__ __launch_bounds__(256) void k_gather(const __bf16* __restrict__ X,
                                                const int* __restrict__ gstart,
                                                const int* __restrict__ gcnt,
                                                float* __restrict__ outp,
                                                float* __restrict__ tcsum) {
    int c = blockIdx.x;
    int col = blockIdx.y * 256 + threadIdx.x;
    int st = gstart[c], n = gcnt[c];
    const __bf16* base = X + (size_t)st * DIM + col;
    float acc = 0.f;
    int i = 0;
    for (; i + 8 <= n; i += 8) {
        float v[8];
        #pragma unroll
        for (int j = 0; j < 8; ++j) v[j] = (float)base[(size_t)(i + j) * DIM];
        #pragma unroll
        for (int j = 0; j < 8; ++j) acc += v[j];
    }
    for (; i < n; ++i) acc += (float)base[(size_t)i * DIM];
    outp[(size_t)c * DIM + col] = acc;
    atomicAdd(&tcsum[col], acc);
}

__global__ __launch_bounds__(512) void k_gemv1(const float* __restrict__ tc,
                                               const float* __restrict__ sp_w1,
                                               float* __restrict__ hpre) {
    __shared__ float tcs[64];
    int tid = threadIdx.x;
    int kb = blockIdx.x * 64;
    if (tid < 64) tcs[tid] = tc[kb + tid] * (1.0f / N_SUP);
    __syncthreads();
    float acc = 0.f;
    #pragma unroll 8
    for (int k = 0; k < 64; ++k)
        acc += tcs[k] * sp_w1[(size_t)(kb + k) * 512 + tid];
    atomicAdd(&hpre[tid], acc);
}

__global__ __launch_bounds__(512) void k_head_fin(const float* __restrict__ hpre,
                                                  const float* __restrict__ sp_b1,
                                                  const float* __restrict__ sp_w2,
                                                  const float* __restrict__ sp_b2,
                                                  float* __restrict__ headf,
                                                  int* __restrict__ headi,
                                                  float* __restrict__ dout) {
    __shared__ float red[512];
    __shared__ float a4[4];
    int tid = threadIdx.x;
    float hv = hpre[tid] + sp_b1[tid];
    hv = hv > 0.f ? hv : 0.f;
    #pragma unroll
    for (int o = 0; o < 4; ++o) {
        red[tid] = hv * sp_w2[tid * 4 + o];
        __syncthreads();
        for (int st = 256; st > 0; st >>= 1) {
            if (tid < st) red[tid] += red[tid + st];
            __syncthreads();
        }
        if (tid == 0) a4[o] = 1.0f / (1.0f + expf(-(red[0] + sp_b2[o])));
        __syncthreads();
    }
    if (tid == 0) {
        int kk = 0;
        int lvl[4] = {-1, -1, -1, -1};
        for (int l = 0; l < 4; ++l)
            if (a4[l] > 0.1f) { lvl[kk] = l; kk++; }
        headi[0] = kk;
        for (int s = 0; s < 4; ++s) headi[1 + s] = lvl[s];
        for (int l = 0; l < 4; ++l) headf[l] = a4[l];
    }
    if (tid < 4) {
        dout[65536 + tid] = a4[tid];
        dout[65540 + tid] = a4[tid] > 0.1f ? a4[tid] : 0.f;
    }
}

// ==================== 256x256 balanced 4-phase bf16 MFMA GEMM ====================
// 8 waves (2M x 4N), BK=64, dbuf 128KB LDS, XOR-swizzle. Reads balanced 6/6/8/4
// per phase; ax of tile t+1 prefetched into registers during tile t (ph2/ph3).
// Stage issue ledger (per wave, 2 loads each): Ap0@ph0, Ap1@ph1, B0@ph2, B1@ph3.
// Drain ledger: ph0 vmcnt(2) drains Ap1,B0,B1(t) [issued 1-3 phases back];
//               ph2 vmcnt(4) drains Ap0(t+1)     [issued 2 phases back].
__global__ __launch_bounds__(512, 2) void k_gemm256(const __bf16* __restrict__ A,
                                                    const __bf16* __restrict__ Bt,
                                                    const float* __restrict__ bias,
                                                    __bf16* __restrict__ C,
                                                    int K, int Nn, int NT) {
    __shared__ __bf16 lds[65536];   // [buf][A|B][half][2 x 64rows][64]
    const int tid = threadIdx.x;
    const int w   = tid >> 6;
    const int l   = tid & 63;
    const int wr  = w >> 2;
    const int wc  = w & 3;
    const int am  = l & 15;
    const int kg  = l >> 4;
    const size_t bm = (size_t)blockIdx.x * 256;
    const size_t bn = (size_t)blockIdx.y * 256;

    const int srow = w * 8 + (l >> 3);
    const int scol = ((l & 7) ^ (l >> 3)) * 8;     // pre-swizzled source col
    const __bf16* gA[2][2]; const __bf16* gB[2][2];
    #pragma unroll
    for (int h = 0; h < 2; ++h)
        #pragma unroll
        for (int p = 0; p < 2; ++p) {
            gA[h][p] = A  + (bm + h * 128 + p * 64 + srow) * (size_t)K + scol;
            gB[h][p] = Bt + (bn + h * 128 + p * 64 + srow) * (size_t)K + scol;
        }

    f32x4 acc[8][4] = {};
    bf16x8 ax[4][2], ay[4][2], bx[2][2], by[2][2];

    // prologue: stage tile 0 (8 chunks), drain, read ax(0)
    #pragma unroll
    for (int h = 0; h < 2; ++h)
        #pragma unroll
        for (int p = 0; p < 2; ++p) {
            GLOAD_LDS16(gA[h][p], lds + h * 8192 + p * 4096 + w * 512);
            GLOAD_LDS16(gB[h][p], lds + 16384 + h * 8192 + p * 4096 + w * 512);
        }
    asm volatile("s_waitcnt vmcnt(0)" ::: "memory");
    __builtin_amdgcn_s_barrier();

    const int swz = (am & 7) * 8;
    const int ko0 = (kg * 8) ^ swz;
    const int ko1 = (32 + kg * 8) ^ swz;
    {
        const __bf16* pa0 = lds + wr * 8192;
        #pragma unroll
        for (int i = 0; i < 4; ++i) {
            ax[i][0] = *(const bf16x8*)(pa0 + (i * 16 + am) * 64 + ko0);
            ax[i][1] = *(const bf16x8*)(pa0 + (i * 16 + am) * 64 + ko1);
        }
    }

#define MFMAQ(qm, qn, AF, BF) \
    __builtin_amdgcn_s_setprio(1); \
    _Pragma("unroll") \
    for (int i_ = 0; i_ < 4; ++i_) \
        _Pragma("unroll") \
        for (int j_ = 0; j_ < 2; ++j_) \
            _Pragma("unroll") \
            for (int k_ = 0; k_ < 2; ++k_) \
                acc[(qm) * 4 + i_][(qn) * 2 + j_] = __builtin_amdgcn_mfma_f32_16x16x32_bf16( \
                    AF[i_][k_], BF[j_][k_], acc[(qm) * 4 + i_][(qn) * 2 + j_], 0, 0, 0); \
    __builtin_amdgcn_s_setprio(0);

    for (int t = 0; t < NT; ++t) {
        const int cb = (t & 1) * 32768;
        const int nb = cb ^ 32768;
        const int tn = (t + 1) * 64;
        const bool more = (t + 1 < NT);
        const __bf16* pa  = lds + cb + wr * 8192;
        const __bf16* pan = lds + nb + wr * 8192;
        const __bf16* pb  = lds + cb + 16384 + (wc >> 1) * 8192 + (wc & 1) * 4096;

        // ---- ph0: issue Ap0(t+1); drain tile t; read bx(4)+ay0(2); MFMA q0 ----
        if (more) {
            GLOAD_LDS16(gA[0][0] + tn, lds + nb + 0 * 4096 + w * 512);
            GLOAD_LDS16(gA[1][0] + tn, lds + nb + 8192 + 0 * 4096 + w * 512);
            asm volatile("s_waitcnt vmcnt(2)" ::: "memory");
        } else {
            asm volatile("s_waitcnt vmcnt(0)" ::: "memory");
        }
        __builtin_amdgcn_s_barrier();
        #pragma unroll
        for (int j = 0; j < 2; ++j) {
            bx[j][0] = *(const bf16x8*)(pb + (j * 16 + am) * 64 + ko0);
            bx[j][1] = *(const bf16x8*)(pb + (j * 16 + am) * 64 + ko1);
        }
        ay[0][0] = *(const bf16x8*)(pa + ((4 + 0) * 16 + am) * 64 + ko0);
        ay[0][1] = *(const bf16x8*)(pa + ((4 + 0) * 16 + am) * 64 + ko1);
        MFMAQ(0, 0, ax, bx)

        // ---- ph1: issue Ap1(t+1); read by(4)+ay1(2); MFMA q1 ----
        if (more) {
            GLOAD_LDS16(gA[0][1] + tn, lds + nb + 1 * 4096 + w * 512);
            GLOAD_LDS16(gA[1][1] + tn, lds + nb + 8192 + 1 * 4096 + w * 512);
        }
        __builtin_amdgcn_s_barrier();
        #pragma unroll
        for (int j = 0; j < 2; ++j) {
            by[j][0] = *(const bf16x8*)(pb + ((2 + j) * 16 + am) * 64 + ko0);
            by[j][1] = *(const bf16x8*)(pb + ((2 + j) * 16 + am) * 64 + ko1);
        }
        ay[1][0] = *(const bf16x8*)(pa + ((4 + 1) * 16 + am) * 64 + ko0);
        ay[1][1] = *(const bf16x8*)(pa + ((4 + 1) * 16 + am) * 64 + ko1);
        MFMAQ(0, 1, ax, by)

        // ---- ph2: issue B0(t+1); drain Ap0(t+1); read ay23(4)+ax'01(4); MFMA q2 ----
        if (more) {
            GLOAD_LDS16(gB[0][0] + tn, lds + nb + 16384 + 0 * 4096 + w * 512);
            GLOAD_LDS16(gB[0][1] + tn, lds + nb + 16384 + 1 * 4096 + w * 512);
            asm volatile("s_waitcnt vmcnt(4)" ::: "memory");
        }
        __builtin_amdgcn_s_barrier();
        #pragma unroll
        for (int i = 2; i < 4; ++i) {
            ay[i][0] = *(const bf16x8*)(pa + ((4 + i) * 16 + am) * 64 + ko0);
            ay[i][1] = *(const bf16x8*)(pa + ((4 + i) * 16 + am) * 64 + ko1);
        }
        if (more) {
            #pragma unroll
            for (int i = 0; i < 2; ++i) {
                ax[i][0] = *(const bf16x8*)(pan + (i * 16 + am) * 64 + ko0);
                ax[i][1] = *(const bf16x8*)(pan + (i * 16 + am) * 64 + ko1);
            }
        }
        MFMAQ(1, 0, ay, bx)

        // ---- ph3: issue B1(t+1); read ax'23(4); MFMA q3 ----
        if (more) {
            GLOAD_LDS16(gB[1][0] + tn, lds + nb + 16384 + 8192 + 0 * 4096 + w * 512);
            GLOAD_LDS16(gB[1][1] + tn, lds + nb + 16384 + 8192 + 1 * 4096 + w * 512);
        }
        __builtin_amdgcn_s_barrier();
        if (more) {
            #pragma unroll
            for (int i = 2; i < 4; ++i) {
                ax[i][0] = *(const bf16x8*)(pan + (i * 16 + am) * 64 + ko0);
                ax[i][1] = *(const bf16x8*)(pan + (i * 16 + am) * 64 + ko1);
            }
        }
        MFMAQ(1, 1, ay, by)
    }
#undef MFMAQ

    const int rbase = kg * 4;    // C/D: col=lane&15, row=(lane>>4)*4+reg
    #pragma unroll
    for (int m = 0; m < 8; ++m) {
        const size_t row = bm + wr * 128 + m * 16 + rbase;
        #pragma unroll
        for (int n = 0; n < 4; ++n) {
            const int col = (int)bn + wc * 64 + n * 16 + am;
            const float bv = bias[col];
            #pragma unroll
            for (int r = 0; r < 4; ++r)
                C[(row + r) * (size_t)Nn + col] = (__bf16)(acc[m][n][r] + bv);
        }
    }
}

// ===== fused LN+ReLU+segment-sum, wave-per-row over SORTED hh =====
// block = (class, level, z of 2); 4 waves; wave handles rows st + (z*4+wv) step 8.
// Lane owns 16 cols; block-reduce in LDS; one atomicAdd per col per block.
__global__ __launch_bounds__(256) void k_gather_ln(const __bf16* __restrict__ hh,
                                                   const float* __restrict__ an_g,
                                                   const float* __restrict__ an_be,
                                                   const int* __restrict__ gstart,
                                                   const int* __restrict__ gcnt,
                                                   float* __restrict__ gsum) {
    int c = blockIdx.x, lv = blockIdx.y, z = blockIdx.z;
    int tid = threadIdx.x;
    int wv = tid >> 6, lane = tid & 63;
    int colb = lane * 16;
    float g[16], b[16];
    #pragma unroll
    for (int j = 0; j < 16; j += 4) {
        float4 gv = *(const float4*)(an_g + lv * 1024 + colb + j);
        float4 bv = *(const float4*)(an_be + lv * 1024 + colb + j);
        g[j] = gv.x; g[j + 1] = gv.y; g[j + 2] = gv.z; g[j + 3] = gv.w;
        b[j] = bv.x; b[j + 1] = bv.y; b[j + 2] = bv.z; b[j + 3] = bv.w;
    }
    int st = gstart[c], n = gcnt[c];
    float acc[16] = {};
    #pragma unroll 2
    for (int i = z * 4 + wv; i < n; i += 8) {
        const __bf16* row = hh + (size_t)(st + i) * NFUSE + lv * 1024 + colb;
        bf16x8 v0 = *(const bf16x8*)row;
        bf16x8 v1 = *(const bf16x8*)(row + 8);
        float x[16];
        #pragma unroll
        for (int j = 0; j < 8; ++j) { x[j] = (float)v0[j]; x[8 + j] = (float)v1[j]; }
        float s = 0.f, q = 0.f;
        #pragma unroll
        for (int j = 0; j < 16; ++j) { s += x[j]; q += x[j] * x[j]; }
        #pragma unroll
        for (int off = 1; off < 64; off <<= 1) {
            s += __shfl_xor(s, off);
            q += __shfl_xor(q, off);
        }
        float mu = s * (1.0f / DIM);
        float var = q * (1.0f / DIM) - mu * mu;
        float rstd = rsqrtf(var + 1e-5f);
        #pragma unroll
        for (int j = 0; j < 16; ++j) {
            float y = (x[j] - mu) * rstd * g[j] + b[j];
            acc[j] += y > 0.f ? y : 0.f;
        }
    }
    __shared__ float red[4][1024];
    #pragma unroll
    for (int j = 0; j < 16; ++j) red[wv][colb + j] = acc[j];
    __syncthreads();
    for (int col = tid; col < 1024; col += 256) {
        float v = red[0][col] + red[1][col] + red[2][col] + red[3][col];
        atomicAdd(&gsum[(size_t)c * NFUSE + lv * 1024 + col], v);
    }
}

// fusion_input build: packed part = proto_pre[l][c][d]/cnt[c] + b2[l][d]
__global__ __launch_bounds__(256) void k_build_fi(const float* __restrict__ proto_pre,
                                                  const float* __restrict__ an_b2,
                                                  const int* __restrict__ gcnt,
                                                  const float* __restrict__ counts_f,
                                                  const float* __restrict__ headf,
                                                  const int* __restrict__ headi,
                                                  float* __restrict__ fi) {
    int idx = blockIdx.x * 256 + threadIdx.x;
    if (idx >= 64 * 4160) return;
    int c = idx / 4160, col = idx % 4160;
    int kk = headi[0];
    float v = 0.f;
    if (col < kk * 1024) {
        int s = col >> 10, d = col & 1023;
        int l = headi[1 + s];
        if (gcnt[c] > 0)
            v = proto_pre[((size_t)l * NCLS + c) * DIM + d] / counts_f[c]
                + an_b2[(size_t)l * DIM + d];
    } else if (col < kk * 1024 + kk) {
        int s = col - kk * 1024;
        v = headf[headi[1 + s]];
    }
    fi[idx] = v;
}

// f32 split-K GEMM (64 x 1024 out), z-strided, atomic accumulate.
// abias != null: A element transformed as relu(a + abias[k]) (valid k only).
__global__ __launch_bounds__(256) void k_fuse_gemm(const float* __restrict__ Abase, int lda, int az,
                                                   const float* __restrict__ Wbase, int wz,
                                                   float* __restrict__ outbase, int oz,
                                                   const float* __restrict__ abias,
                                                   int K) {
    const float* Afi = Abase + (size_t)blockIdx.z * az;
    const float* W   = Wbase + (size_t)blockIdx.z * wz;
    float* outp      = outbase + (size_t)blockIdx.z * oz;
    __shared__ float fi_lds[64][64];
    int tid = threadIdx.x;
    int tj = tid & 63, tg = tid >> 6;
    int jb = blockIdx.x;
    int k0 = blockIdx.y * 64;
    for (int i = tid; i < 64 * 64; i += 256) {
        int cc = i >> 6, kq = i & 63;
        float av = 0.f;
        if (k0 + kq < lda) {
            av = Afi[(size_t)cc * lda + k0 + kq];
            if (abias) {
                av += abias[k0 + kq];
                av = av > 0.f ? av : 0.f;
            }
        }
        fi_lds[cc][kq] = av;
    }
    __syncthreads();
    float acc[16] = {};
    #pragma unroll 4
    for (int kq = 0; kq < 64; ++kq) {
        int kg = k0 + kq;
        float wv = (kg < K) ? W[(size_t)kg * 1024 + jb * 64 + tj] : 0.f;
        #pragma unroll
        for (int cc = 0; cc < 16; ++cc)
            acc[cc] += fi_lds[tg * 16 + cc][kq] * wv;
    }
    #pragma unroll
    for (int cc = 0; cc < 16; ++cc)
        atomicAdd(&outp[(size_t)(tg * 16 + cc) * 1024 + jb * 64 + tj], acc[cc]);
}

__global__ __launch_bounds__(256) void k_final(const float* __restrict__ pre2,
                                               const float* __restrict__ fu_b2,
                                               const int* __restrict__ headi,
                                               const float* __restrict__ rawsum,
                                               const float* __restrict__ counts_f,
                                               float* __restrict__ dout) {
    int i = blockIdx.x * 256 + threadIdx.x;   // 65536
    int c = i >> 10, j = i & 1023;
    float v;
    if (headi[0] > 0) v = pre2[i] + fu_b2[j];
    else              v = rawsum[i] / counts_f[c];
    dout[i] = v;
}

extern "C" void kernel_launch(void* const* d_in, const int* in_sizes, int n_in,
                              void* d_out, int out_size, void* d_ws, size_t ws_size,
                              hipStream_t stream) {
    (void)in_sizes; (void)n_in; (void)out_size; (void)ws_size;
    const float* feat    = (const float*)d_in[0];
    const int*   labels  = (const int*)d_in[1];
    const float* sp_w1   = (const float*)d_in[2];
    const float* sp_b1   = (const float*)d_in[3];
    const float* sp_w2   = (const float*)d_in[4];
    const float* sp_b2   = (const float*)d_in[5];
    const float* lvl_emb = (const float*)d_in[6];
    const float* an_w1   = (const float*)d_in[7];
    const float* an_b1   = (const float*)d_in[8];
    const float* an_g    = (const float*)d_in[9];
    const float* an_be   = (const float*)d_in[10];
    const float* an_w2   = (const float*)d_in[11];
    const float* an_b2   = (const float*)d_in[12];
    const float* fu_w1   = (const float*)d_in[13];
    const float* fu_b1   = (const float*)d_in[14];
    const float* fu_w2   = (const float*)d_in[15];
    const float* fu_b2   = (const float*)d_in[16];
    float* dout = (float*)d_out;

    char* p = (char*)d_ws;
    auto alloc = [&](size_t b) { char* r = p; p += (b + 255) & ~(size_t)255; return r; };
    __bf16* featb = (__bf16*)alloc((size_t)N_SUP * DIM * 2);
    __bf16* w1t   = (__bf16*)alloc((size_t)NLV * DIM * DIM * 2);
    __bf16* hh    = (__bf16*)alloc((size_t)N_SUP * NFUSE * 2);
    float*  effb1 = (float*) alloc((size_t)NLV * DIM * 4);
    float*  fi    = (float*) alloc((size_t)64 * 4160 * 4);
    float*  rawsum  = (float*)alloc((size_t)NCLS * DIM * 4);
    int*    inv     = (int*)  alloc((size_t)N_SUP * 4);
    int*    gstart  = (int*)  alloc(NCLS * 4);
    int*    gcnt    = (int*)  alloc(NCLS * 4);
    float*  counts_f= (float*)alloc(NCLS * 4);
    float*  headf   = (float*)alloc(4 * 4);
    int*    headi   = (int*)  alloc(8 * 4);
    char* z0 = p;
    float*  tc      = (float*)alloc(DIM * 4);
    float*  gsum    = (float*)alloc((size_t)NCLS * NFUSE * 4);
    float*  proto_pre = (float*)alloc((size_t)NLV * NCLS * DIM * 4);
    float*  h1pre   = (float*)alloc((size_t)NCLS * DIM * 4);
    float*  f2pre   = (float*)alloc((size_t)NCLS * DIM * 4);
    float*  hpre    = (float*)alloc(512 * 4);
    size_t zbytes = (size_t)(p - z0);
    hipMemsetAsync(z0, 0, zbytes, stream);

    k_eff_b1<<<16, 256, 0, stream>>>(an_w1, an_b1, lvl_emb, effb1);
    k_rowlist<<<1, 1024, 0, stream>>>(labels, inv, gstart, gcnt, counts_f);
    k_conv_feat<<<N_SUP, 256, 0, stream>>>(feat, inv, featb);
    k_wt<<<dim3(16, 16, 4), 256, 0, stream>>>(an_w1, w1t);
    k_gather<<<dim3(NCLS, 4), 256, 0, stream>>>(featb, gstart, gcnt, rawsum, tc);
    k_gemv1<<<16, 512, 0, stream>>>(tc, sp_w1, hpre);
    k_head_fin<<<1, 512, 0, stream>>>(hpre, sp_b1, sp_w2, sp_b2, headf, headi, dout);

    // fused 4-level GEMM1 (rows in class-sorted order)
    k_gemm256<<<dim3(64, 16), 512, 0, stream>>>(featb, w1t, effb1, hh, DIM, NFUSE, DIM / 64);
    // fused LN+ReLU+segment-sum (contiguous class ranges)
    k_gather_ln<<<dim3(NCLS, NLV, 2), 256, 0, stream>>>(hh, an_g, an_be, gstart, gcnt, gsum);
    // proto_pre[l] = gsum[:, l*1024:+1024] @ an_w2[l]  (count-division in build_fi)
    k_fuse_gemm<<<dim3(16, 16, 4), 256, 0, stream>>>(gsum, NFUSE, 1024,
                                                     an_w2, 1024 * 1024,
                                                     proto_pre, NCLS * DIM, nullptr, 1024);

    k_build_fi<<<(64 * 4160) / 256, 256, 0, stream>>>(proto_pre, an_b2, gcnt, counts_f,
                                                      headf, headi, fi);
    k_fuse_gemm<<<dim3(16, 65, 1), 256, 0, stream>>>(fi, 4160, 0, fu_w1, 0,
                                                     h1pre, 0, nullptr, 4100);
    k_fuse_gemm<<<dim3(16, 16, 1), 256, 0, stream>>>(h1pre, 1024, 0, fu_w2, 0,
                                                     f2pre, 0, fu_b1, 1024);
    k_final<<<NCLS * DIM / 256, 256, 0, stream>>>(f2pre, fu_b2, headi, rawsum, counts_f, dout);
}